// Round 8
// baseline (208.555 us; speedup 1.0000x reference)
//
#include <hip/hip_runtime.h>
#include <hip/hip_bf16.h>

#define NN 268
#define NE 8192
#define KP 288   // padded node dim (268 -> 288)

typedef short short8 __attribute__((ext_vector_type(8)));   // 8 bf16 = 4 VGPR
typedef short short4v __attribute__((ext_vector_type(4)));  // 4 bf16 = 8B
typedef float f32x4 __attribute__((ext_vector_type(4)));

__device__ __forceinline__ short f2bf(float f) {
  __hip_bfloat16 h = __float2bfloat16(f);
  return *reinterpret_cast<short*>(&h);
}

// ---------------------------------------------------------------------------
// Workspace (bytes). Peak 57,744,384.
//   OFF_DINV  dinv  f32 [128][272]           139,264
//   OFF_ARENA Y2t   bf16[128][64][288]     4,718,592  (gemm1 out, mega in)
//   OFF_WBT   WbT   bf16[192][288]           110,592  (prep out, gemm1 in)
//   OFF_WC1BT Wc1bT bf16[112][288]            64,512
//   OFF_W4BT  W4bT  bf16[96][64]              12,288
//   OFF_LB    Lb    bf16[128][272][288]   20,054,016
//   OFF_Y     Y     f32 [128][268][192]   26,345,472
//   OFF_META  meta  u16 [128][8192]        2,097,152  (prep out, build in)
//   OFF_WE    we    f32 [128][8192]        4,194,304  (bucketed edge weights)
//   OFF_BCNT  bcnt  u32 [128][8]               4,096  (bucket counts)
//   OFF_BST   bst   u32 [128][8]               4,096  (bucket starts)
// Math BIT-IDENTICAL to R1/R5/R7: bucketing only reorders the int fixed-point
// addends (order-independent); mega's reg-cached L reads the same bytes.
// ---------------------------------------------------------------------------
#define OFF_DINV  0
#define OFF_ARENA 139264
#define ARENA_SLAB_S 18432   // shorts per graph: Y2t [64][288]
#define OFF_WBT   4857856
#define OFF_WC1BT 4968448
#define OFF_W4BT  5032960
#define OFF_LB    5045248
#define OFF_Y     25099264
#define OFF_META  51444736
#define OFF_WE    53541888
#define OFF_BCNT  57736192
#define OFF_BST   57740288

// ---------------------------------------------------------------------------
// K1: prep. 344 blocks.
//  [0,128):   per-graph: degree -> dinv, PLUS edge bucketing by d-tile
//             (8 buckets of 34 rows): histogram + prefix + scatter
//             (meta = d_local<<9 | s, we = w) for the build family.
//  [128,344): WbT conversion (gemm1 input).
// ---------------------------------------------------------------------------
__global__ __launch_bounds__(256) void k_prep(
    const int* __restrict__ ei1, const float* __restrict__ ea1,
    const int* __restrict__ ei2, const float* __restrict__ ea2,
    const float* __restrict__ W1, short* __restrict__ WbT,
    float* __restrict__ dinv, unsigned short* __restrict__ meta,
    float* __restrict__ we, unsigned* __restrict__ bcnt,
    unsigned* __restrict__ bst) {
  int t = threadIdx.x;
  int b = blockIdx.x;
  if (b < 128) {
    int g = b;
    const int* ei = (g < 64) ? (ei1 + (size_t)g * 2 * NE) : (ei2 + (size_t)(g - 64) * 2 * NE);
    const float* ea = (g < 64) ? (ea1 + (size_t)g * NE) : (ea2 + (size_t)(g - 64) * NE);
    __shared__ unsigned degL[NN];
    __shared__ unsigned bc[8], bs[8], bcur[8];
    for (int n = t; n < NN; n += 256) degL[n] = 0u;
    if (t < 8) bc[t] = 0u;
    __syncthreads();
#pragma unroll 4
    for (int e = t; e < NE; e += 256) {       // scan 1: degree + histogram
      int s = ei[e], d = ei[NE + e];
      float w = ea[e];
      if (s != d) {
        atomicAdd(&degL[s], (unsigned)lrintf(w * 1048576.f));
        atomicAdd(&bc[d / 34], 1u);
      }
    }
    __syncthreads();
    for (int n = t; n < 272; n += 256) {
      float r = 0.f;
      if (n < NN) {
        unsigned v = degL[n];
        if (v) r = rsqrtf((float)v * (1.f / 1048576.f));
      }
      dinv[(size_t)g * 272 + n] = r;
    }
    if (t == 0) {                             // prefix
      unsigned run = (unsigned)g * NE;
#pragma unroll
      for (int k = 0; k < 8; ++k) { bs[k] = run; run += bc[k]; }
    }
    __syncthreads();
    if (t < 8) {
      bcnt[g * 8 + t] = bc[t];
      bst[g * 8 + t] = bs[t];
      bcur[t] = bs[t];
    }
    __syncthreads();
#pragma unroll 4
    for (int e = t; e < NE; e += 256) {       // scan 2: scatter
      int s = ei[e], d = ei[NE + e];
      float w = ea[e];
      if (s != d) {
        int bk = d / 34;
        unsigned pos = atomicAdd(&bcur[bk], 1u);
        meta[pos] = (unsigned short)(((d - bk * 34) << 9) | s);
        we[pos] = w;
      }
    }
  } else {
    int idx = (b - 128) * 256 + t;  // 0..55295 = 192*288
    int n = idx / KP, kp = idx - n * KP;
    int kb = n >> 6, j = n & 63;
    float v = (kp < 268) ? W1[((size_t)kb * 268 + kp) * 64 + j] : 0.f;
    WbT[idx] = f2bf(v);
  }
}

// ---------------------------------------------------------------------------
// K2: fused Laplacian build + gemm1 + Wc1bT/W4bT tail. 1814 blocks.
//  [0,640):     gemm1 (MFMA), WbT B, A/B reg-prefetch (R7 verbatim).
//  [640,1664):  Laplacian 34-row tiles FROM BUCKETS: each block reads only
//               its own ~1024 bucketed edges (8x less scan than R7).
//  [1664,1814): Wc1bT / W4bT conversion (mega inputs).
// ---------------------------------------------------------------------------
__global__ __launch_bounds__(256) void k_build_gemm1(
    const unsigned short* __restrict__ meta, const float* __restrict__ we,
    const unsigned* __restrict__ bcnt, const unsigned* __restrict__ bst,
    const float* __restrict__ dinv_all, short* __restrict__ Lb,
    const float* __restrict__ x1, const float* __restrict__ x2,
    const short* __restrict__ WbT, const float* __restrict__ Wc1,
    const float* __restrict__ W4, float* __restrict__ Y,
    short* __restrict__ Y2t, short* __restrict__ Wc1bT,
    short* __restrict__ W4bT) {
  __shared__ __align__(16) char smem[34 * 288 * 4 + 272 * 4];  // 40,256 B
  int t = threadIdx.x;
  int bx = blockIdx.x;
  if (bx < 640) {
    // ===================== gemm1 (MFMA, A/B prefetched) ====================
    int xcd = bx & 7, rest = bx >> 3;       // rest 0..79
    int g = xcd + 8 * (rest / 5);           // graph on XCD g&7
    int m0 = (rest % 5) * 64;
    const float* A32 = (g < 64) ? (x1 + (size_t)g * NN * 268)
                                : (x2 + (size_t)(g - 64) * NN * 268);
    float* Yg = Y + (size_t)g * NN * 192;
    short* Y2tg = Y2t + (size_t)g * ARENA_SLAB_S;
    short (*As)[40] = (short(*)[40])smem;                     //  5,120 B
    short (*Bs)[40] = (short(*)[40])(smem + 5120);            // 15,360 B
    int w = t >> 6, lane = t & 63;
    int quad = lane >> 4, l16 = lane & 15;
    int mh = w & 1, nh = w >> 1;
    f32x4 acc[2][6];
#pragma unroll
    for (int mi = 0; mi < 2; ++mi)
#pragma unroll
      for (int ni = 0; ni < 6; ++ni) acc[mi][ni] = (f32x4){0.f, 0.f, 0.f, 0.f};

    int sr = t >> 2, sko = (t & 3) * 8;
    float4 pva, pvb;
    short8 pB[3];
    auto loadA = [&](int K0) {
      int row = m0 + sr, k = K0 + sko;
      pva = make_float4(0.f, 0.f, 0.f, 0.f); pvb = pva;
      if (row < NN && k < 268) pva = *(const float4*)(A32 + (size_t)row * 268 + k);
      if (row < NN && k + 4 < 268) pvb = *(const float4*)(A32 + (size_t)row * 268 + k + 4);
    };
    auto loadB = [&](int K0) {
#pragma unroll
      for (int i = 0; i < 3; ++i)
        pB[i] = *(const short8*)(WbT + (size_t)(sr + i * 64) * KP + K0 + sko);
    };
    loadA(0); loadB(0);
    for (int k0 = 0; k0 < KP; k0 += 32) {
      {
        short8 s;
        const float* fa = (const float*)&pva;
        const float* fb = (const float*)&pvb;
#pragma unroll
        for (int j = 0; j < 4; ++j) { s[j] = f2bf(fa[j]); s[4 + j] = f2bf(fb[j]); }
        *(short8*)(&As[sr][sko]) = s;
      }
#pragma unroll
      for (int i = 0; i < 3; ++i)
        *(short8*)(&Bs[sr + i * 64][sko]) = pB[i];
      __syncthreads();
      if (k0 + 32 < KP) { loadA(k0 + 32); loadB(k0 + 32); }  // hides under MFMA
      short8 af[2], bfr[6];
#pragma unroll
      for (int mi = 0; mi < 2; ++mi)
        af[mi] = *(const short8*)(&As[(mh * 2 + mi) * 16 + l16][quad * 8]);
#pragma unroll
      for (int ni = 0; ni < 6; ++ni)
        bfr[ni] = *(const short8*)(&Bs[(nh * 6 + ni) * 16 + l16][quad * 8]);
#pragma unroll
      for (int mi = 0; mi < 2; ++mi)
#pragma unroll
        for (int ni = 0; ni < 6; ++ni)
          acc[mi][ni] = __builtin_amdgcn_mfma_f32_16x16x32_bf16(af[mi], bfr[ni], acc[mi][ni], 0, 0, 0);
      __syncthreads();
    }
    // C/D: col = lane&15, row = quad*4 + reg
#pragma unroll
    for (int mi = 0; mi < 2; ++mi) {
      int rbase = m0 + (mh * 2 + mi) * 16 + quad * 4;
#pragma unroll
      for (int reg = 0; reg < 4; ++reg) {
        int row = rbase + reg;
        if (row < NN) {
#pragma unroll
          for (int ni = 0; ni < 6; ++ni) {
            int col = (nh * 6 + ni) * 16 + l16;
            Yg[(size_t)row * 192 + col] = acc[mi][ni][reg];
          }
        }
      }
      if (rbase < NN) {  // rbase % 4 == 0, never straddles 268
#pragma unroll
        for (int ni = 0; ni < 6; ++ni) {
          int col = (nh * 6 + ni) * 16 + l16;
          if (col >= 128) {
            short4v p;
#pragma unroll
            for (int reg = 0; reg < 4; ++reg) p[reg] = f2bf(acc[mi][ni][reg]);
            *(short4v*)(Y2tg + (size_t)(col - 128) * KP + rbase) = p;
          }
        }
      }
    }
  } else if (bx < 1664) {
    // ============ Laplacian build from buckets (8x less scanning) ==========
    int l = bx - 640;                // 0..1023 = 8 xcd * 16 g * 8 tiles
    int xcd = l & 7, rest = l >> 3;  // rest 0..127
    int g = xcd + 8 * (rest & 15);
    int tile = rest >> 4;            // 0..7
    int r0 = tile * 34;
    int* LrowI = (int*)smem;                      // 34*288 ints = 39,168 B
    float* dv = (float*)(smem + 39168);           // 272 floats
    for (int i = t; i < 34 * 288; i += 256) LrowI[i] = 0;
    for (int i = t; i < 272; i += 256) dv[i] = dinv_all[(size_t)g * 272 + i];
    __syncthreads();
    unsigned n = bcnt[g * 8 + tile];
    unsigned base = bst[g * 8 + tile];
    for (unsigned i = t; i < n; i += 256) {
      unsigned m = meta[base + i];
      float w = we[base + i];
      int dl = m >> 9, s = m & 511;
      atomicAdd(&LrowI[dl * 288 + s],
                (int)lrintf(-dv[s] * w * dv[r0 + dl] * 16777216.f));  // ds_add
    }
    __syncthreads();
    short* Lbg = Lb + (size_t)g * 272 * KP + (size_t)r0 * KP;
    for (int i = t; i < 34 * 288; i += 256)
      Lbg[i] = f2bf((float)LrowI[i] * (1.f / 16777216.f));
  } else {
    // ===================== Wc1bT / W4bT tail (mega inputs) =================
    int idx = (bx - 1664) * 256 + t;  // 0..38399
    if (idx < 112 * KP) {
      int n = idx / KP, k = idx - n * KP;
      float v = (n < 100 && k < 268) ? Wc1[(size_t)k * 100 + n] : 0.f;
      Wc1bT[idx] = f2bf(v);
    } else {
      int i4 = idx - 112 * KP;       // 0..6143
      int n = i4 >> 6, k = i4 & 63;  // n in [0,96), k in [0,64)
      W4bT[i4] = f2bf(W4[(((size_t)(n >> 5)) * 64 + k) * 32 + (n & 31)]);
    }
  }
}

// ---------------------------------------------------------------------------
// K3: MEGA — round-5 structure (512 thr, measured 49.7) with ONE change:
// the per-wave L A-fragments (3 tiles x 9 short8) are loaded ONCE before P0
// (global-load latency overlaps Y2t staging) and reused across P1/P2/P4/P5 —
// removing every global A-load stall from the four L-apply phases.
// VGPR +108 (~200 total), still fine for 8 waves at 1 block/CU (LDS-bound).
// ---------------------------------------------------------------------------
#define SP 296
#define YT2_O  0
#define H1N_O  0
#define UT_O   40960
#define UT2_O  40960
#define H2T_O  59904
#define W4S_O  78848
#define YBT_O  92672
#define Z1_O   0
#define W2S_O  14848
#define Z2_O   78848
#define W3S_O  87040
#define SM_SZ  111616
#define NW     8       // waves per mega block
#define NTHR   512

__device__ __forceinline__ void load_a9(const short* __restrict__ Lbg,
                                        int mt, int l16, int quad, short8* a9) {
  const short* Arow = Lbg + (size_t)(mt * 16 + l16) * KP + quad * 8;
#pragma unroll
  for (int k = 0; k < 9; ++k) a9[k] = *(const short8*)(Arow + k * 32);
}

template <int NTN>
__device__ __forceinline__ void cheb_mm_pre(const short8* a9,
                                            const char* B0, int l16, int quad,
                                            f32x4* acc) {
#pragma unroll
  for (int k = 0; k < 9; ++k) {
#pragma unroll
    for (int nt = 0; nt < NTN; ++nt) {
      short8 bf = *(const short8*)(B0 +
          ((size_t)(nt * 16 + l16) * SP + k * 32 + quad * 8) * 2);
      acc[nt] = __builtin_amdgcn_mfma_f32_16x16x32_bf16(a9[k], bf, acc[nt], 0, 0, 0);
    }
  }
}

__global__ __launch_bounds__(NTHR, 1) void k_mega(
    const short* __restrict__ Lb, const short* __restrict__ arena,
    float* __restrict__ Y, const short* __restrict__ W4bT,
    const short* __restrict__ Wc1bT,
    const float* __restrict__ b1, const float* __restrict__ b4,
    const float* __restrict__ bc1, const float* __restrict__ Wc2,
    const float* __restrict__ bc2, const float* __restrict__ Wc3,
    const float* __restrict__ bc3, float* __restrict__ out) {
  __shared__ __align__(16) char sm[SM_SZ];
  int g = blockIdx.x;
  int t = threadIdx.x;
  int w = t >> 6, lane = t & 63;
  int quad = lane >> 4, l16 = lane & 15;
  const short* Lbg = Lb + (size_t)g * 272 * KP;
  const short* Y2tg = arena + (size_t)g * ARENA_SLAB_S;
  float* Yg = Y + (size_t)g * NN * 192;

  // ---- hoisted L fragments: tiles mt = w, w+8 (always <17), 16 (w==0) ----
  short8 aL0[9], aL1[9], aL2[9];
  load_a9(Lbg, w, l16, quad, aL0);
  load_a9(Lbg, w + 8, l16, quad, aL1);
  if (w == 0) load_a9(Lbg, 16, l16, quad, aL2);

  // ---- P0: Y2t -> LDS [64][SP]; cols >=268 forced to 0 (poison-safe) ----
  for (int i = t; i < 64 * 37; i += NTHR) {
    int r = i / 37, c = (i - r * 37) * 8;
    short8 v = {0, 0, 0, 0, 0, 0, 0, 0};
    if (c < 264) {
      v = *(const short8*)(Y2tg + (size_t)r * KP + c);
    } else if (c == 264) {
      v = *(const short8*)(Y2tg + (size_t)r * KP + 264);
      v[4] = 0; v[5] = 0; v[6] = 0; v[7] = 0;
    }
    *(short8*)(sm + YT2_O + ((size_t)r * SP + c) * 2) = v;
  }
  // zero Ut node-pad cols 268..287 (Ut region disjoint of Y2t)
  for (int i = t; i < 64 * 20; i += NTHR) {
    int f = i / 20, d = 268 + (i - f * 20);
    *(short*)(sm + UT_O + ((size_t)f * SP + d) * 2) = 0;
  }
  __syncthreads();

  // ---- P1: Ut[f][d] = bf16(Y1[d][f] + 2*(L@Y2)[d][f]) ----
  {
    auto body = [&](int mt, const short8* a9) {
      int dbase = mt * 16 + quad * 4;
      float yr[4][4];
      if (dbase < NN) {
#pragma unroll
        for (int nt = 0; nt < 4; ++nt)
#pragma unroll
          for (int reg = 0; reg < 4; ++reg)
            yr[nt][reg] = Yg[(size_t)(dbase + reg) * 192 + 64 + nt * 16 + l16];
      }
      f32x4 acc[4];
#pragma unroll
      for (int nt = 0; nt < 4; ++nt) acc[nt] = (f32x4){0.f, 0.f, 0.f, 0.f};
      cheb_mm_pre<4>(a9, sm + YT2_O, l16, quad, acc);
      if (dbase < NN) {
#pragma unroll
        for (int nt = 0; nt < 4; ++nt) {
          int f = nt * 16 + l16;
          short4v p;
#pragma unroll
          for (int reg = 0; reg < 4; ++reg)
            p[reg] = f2bf(yr[nt][reg] + 2.f * acc[nt][reg]);
          *(short4v*)(sm + UT_O + ((size_t)f * SP + dbase) * 2) = p;
        }
      }
    };
    body(w, aL0); body(w + 8, aL1); if (w == 0) body(16, aL2);
  }
  __syncthreads();

  // ---- P2: H1n[d][f] = relu(Y0 - Y2 + (L@Ut)[d][f] + b1[f]), stride 72 ----
  {
    auto body = [&](int mt, const short8* a9) {
      int dbase = mt * 16 + quad * 4;
      float yr0[4][4], yr2[4][4];
      if (dbase < NN) {
#pragma unroll
        for (int nt = 0; nt < 4; ++nt)
#pragma unroll
          for (int reg = 0; reg < 4; ++reg) {
            int f = nt * 16 + l16;
            yr0[nt][reg] = Yg[(size_t)(dbase + reg) * 192 + f];
            yr2[nt][reg] = Yg[(size_t)(dbase + reg) * 192 + 128 + f];
          }
      }
      f32x4 acc[4];
#pragma unroll
      for (int nt = 0; nt < 4; ++nt) acc[nt] = (f32x4){0.f, 0.f, 0.f, 0.f};
      cheb_mm_pre<4>(a9, sm + UT_O, l16, quad, acc);
      if (dbase < NN) {
#pragma unroll
        for (int nt = 0; nt < 4; ++nt) {
          int f = nt * 16 + l16;
          float bb = b1[f];
#pragma unroll
          for (int reg = 0; reg < 4; ++reg) {
            int d = dbase + reg;
            float v = yr0[nt][reg] - yr2[nt][reg] + acc[nt][reg] + bb;
            *(short*)(sm + H1N_O + ((size_t)d * 72 + f) * 2) = f2bf(fmaxf(v, 0.f));
          }
        }
      }
    };
    body(w, aL0); body(w + 8, aL1); if (w == 0) body(16, aL2);
  }
  __syncthreads();

  // ---- P3: Yb^T[c][d] = (H1 @ W4)[d][c]; c<64 -> Yg[d][c] f32,
  //          c>=64 -> Yg[d][c+96] f32 + YBT (Yb2t bf16) ----
  for (int i = t; i < 96 * 8; i += NTHR) {  // stage W4s [96][72]
    int r = i >> 3, ko = (i & 7) * 8;
    *(short8*)(sm + W4S_O + ((size_t)r * 72 + ko) * 2) =
        *(const short8*)(W4bT + r * 64 + ko);
  }
  for (int i = t; i < 32 * 20; i += NTHR) { // zero YBT node-pads
    int f = i / 20, d = 268 + (i - f * 20);
    *(short*)(sm + YBT_O + ((size_t)f * SP + d) * 2) = 0;
  }
  __syncthreads();
  for (int id = w; id < 102; id += NW) {    // 6 c-tiles x 17 d-tiles
    int mt = id / 17, nt = id - mt * 17;
    f32x4 a1 = (f32x4){0.f, 0.f, 0.f, 0.f};
#pragma unroll
    for (int kc = 0; kc < 2; ++kc) {
      short8 af = *(const short8*)(sm + W4S_O +
          ((size_t)(mt * 16 + l16) * 72 + kc * 32 + quad * 8) * 2);
      short8 bf = *(const short8*)(sm + H1N_O +
          ((size_t)(nt * 16 + l16) * 72 + kc * 32 + quad * 8) * 2);
      a1 = __builtin_amdgcn_mfma_f32_16x16x32_bf16(af, bf, a1, 0, 0, 0);
    }
    int d = nt * 16 + l16;
    if (d < NN) {
      int c0 = mt * 16 + quad * 4;
#pragma unroll
      for (int reg = 0; reg < 4; ++reg) {
        int c = c0 + reg;
        float a = a1[reg];
        Yg[(size_t)d * 192 + ((c < 64) ? c : c + 96)] = a;
        if (c >= 64)
          *(short*)(sm + YBT_O + ((size_t)(c - 64) * SP + d) * 2) = f2bf(a);
      }
    }
  }
  __syncthreads();

  // ---- P4: Ut2[f][d] = bf16(Yb1[d][f] + 2*(L@Yb2)[d][f]) ----
  for (int i = t; i < 32 * 20; i += NTHR) {
    int f = i / 20, d = 268 + (i - f * 20);
    *(short*)(sm + UT2_O + ((size_t)f * SP + d) * 2) = 0;
  }
  __syncthreads();
  {
    auto body = [&](int mt, const short8* a9) {
      int dbase = mt * 16 + quad * 4;
      float yr[2][4];
      if (dbase < NN) {
#pragma unroll
        for (int nt = 0; nt < 2; ++nt)
#pragma unroll
          for (int reg = 0; reg < 4; ++reg)
            yr[nt][reg] = Yg[(size_t)(dbase + reg) * 192 + 32 + nt * 16 + l16];
      }
      f32x4 acc[2];
#pragma unroll
      for (int nt = 0; nt < 2; ++nt) acc[nt] = (f32x4){0.f, 0.f, 0.f, 0.f};
      cheb_mm_pre<2>(a9, sm + YBT_O, l16, quad, acc);
      if (dbase < NN) {
#pragma unroll
        for (int nt = 0; nt < 2; ++nt) {
          int f = nt * 16 + l16;
          short4v p;
#pragma unroll
          for (int reg = 0; reg < 4; ++reg)
            p[reg] = f2bf(yr[nt][reg] + 2.f * acc[nt][reg]);
          *(short4v*)(sm + UT2_O + ((size_t)f * SP + dbase) * 2) = p;
        }
      }
    };
    body(w, aL0); body(w + 8, aL1); if (w == 0) body(16, aL2);
  }
  __syncthreads();

  // ---- P5: H2T[f][d] = relu(Yb0 - Yb2 + (L@Ut2)[d][f] + b4[f]) ----
  for (int i = t; i < 32 * 20; i += NTHR) {
    int f = i / 20, d = 268 + (i - f * 20);
    *(short*)(sm + H2T_O + ((size_t)f * SP + d) * 2) = 0;
  }
  __syncthreads();
  {
    auto body = [&](int mt, const short8* a9) {
      int dbase = mt * 16 + quad * 4;
      float yr0[2][4], yr2[2][4];
      if (dbase < NN) {
#pragma unroll
        for (int nt = 0; nt < 2; ++nt)
#pragma unroll
          for (int reg = 0; reg < 4; ++reg) {
            int f = nt * 16 + l16;
            yr0[nt][reg] = Yg[(size_t)(dbase + reg) * 192 + f];
            yr2[nt][reg] = Yg[(size_t)(dbase + reg) * 192 + 160 + f];
          }
      }
      f32x4 acc[2];
#pragma unroll
      for (int nt = 0; nt < 2; ++nt) acc[nt] = (f32x4){0.f, 0.f, 0.f, 0.f};
      cheb_mm_pre<2>(a9, sm + UT2_O, l16, quad, acc);
      if (dbase < NN) {
#pragma unroll
        for (int nt = 0; nt < 2; ++nt) {
          int f = nt * 16 + l16;
          float bb = b4[f];
          short4v p;
#pragma unroll
          for (int reg = 0; reg < 4; ++reg) {
            float v = yr0[nt][reg] - yr2[nt][reg] + acc[nt][reg] + bb;
            p[reg] = f2bf(fmaxf(v, 0.f));
          }
          *(short4v*)(sm + H2T_O + ((size_t)f * SP + dbase) * 2) = p;
        }
      }
    };
    body(w, aL0); body(w + 8, aL1); if (w == 0) body(16, aL2);
  }
  __syncthreads();

  // ---- P6: classifier. L1: MFMA 32x112 K=288 (A=H2T LDS, B=Wc1bT global) ----
  for (int id = w; id < 14; id += NW) {     // 2 m-tiles x 7 n-tiles
    int mt = id & 1, nt = id >> 1;
    f32x4 a1 = (f32x4){0.f, 0.f, 0.f, 0.f};
#pragma unroll
    for (int k = 0; k < 9; ++k) {
      short8 af = *(const short8*)(sm + H2T_O +
          ((size_t)(mt * 16 + l16) * SP + k * 32 + quad * 8) * 2);
      short8 bf = *(const short8*)(Wc1bT + (size_t)(nt * 16 + l16) * KP + k * 32 + quad * 8);
      a1 = __builtin_amdgcn_mfma_f32_16x16x32_bf16(af, bf, a1, 0, 0, 0);
    }
    int col = nt * 16 + l16;
    if (col < 100) {
      float bb = bc1[col];
      int r0 = mt * 16 + quad * 4;
#pragma unroll
      for (int reg = 0; reg < 4; ++reg)
        *(float*)(sm + Z1_O + ((size_t)(r0 + reg) * 116 + col) * 4) =
            fmaxf(a1[reg] + bb, 0.f);
    }
  }
  for (int i = t; i < 100 * 64; i += NTHR) { // stage W2s [100][64]
    int rr = i >> 6, c = i & 63;
    *(float*)(sm + W2S_O + ((size_t)rr * 64 + c) * 4) =
        (c < 60) ? Wc2[(size_t)rr * 60 + c] : 0.f;
  }
  if (t < 64) *(float*)(sm + W3S_O + (size_t)t * 4) = (t < 60) ? Wc3[t] : 0.f;
  __syncthreads();
  if (t < 128) {                             // L2: Z2 = relu(Z1@Wc2+bc2)
    int r2 = (t >> 3) * 2;
    int c8 = (t & 7) * 8;
    float a2[2][8];
#pragma unroll
    for (int i = 0; i < 2; ++i)
#pragma unroll
      for (int j = 0; j < 8; ++j) a2[i][j] = 0.f;
    const float* Z1p = (const float*)(sm + Z1_O);
    const float* W2p = (const float*)(sm + W2S_O);
#pragma unroll 4
    for (int k = 0; k < 100; ++k) {
      float x0 = Z1p[(size_t)r2 * 116 + k], x1 = Z1p[(size_t)(r2 + 1) * 116 + k];
      float4 wA = *(const float4*)(W2p + (size_t)k * 64 + c8);
      float4 wB = *(const float4*)(W2p + (size_t)k * 64 + c8 + 4);
      float wv[8] = {wA.x, wA.y, wA.z, wA.w, wB.x, wB.y, wB.z, wB.w};
#pragma unroll
      for (int j = 0; j < 8; ++j) { a2[0][j] += x0 * wv[j]; a2[1][j] += x1 * wv[j]; }
    }
    float* Z2p = (float*)(sm + Z2_O);
#pragma unroll
    for (int j = 0; j < 8; ++j) {
      int c = c8 + j;
      float bb = (c < 60) ? bc2[c] : 0.f;
      Z2p[(size_t)r2 * 64 + c] = fmaxf(a2[0][j] + bb, 0.f);
      Z2p[(size_t)(r2 + 1) * 64 + c] = fmaxf(a2[1][j] + bb, 0.f);
    }
  }
  __syncthreads();
  if (t < 32) {                              // L3: out = Z2 . Wc3 + bc3
    const float* Z2p = (const float*)(sm + Z2_O);
    const float* w3p = (const float*)(sm + W3S_O);
    float acc3 = bc3[0];
#pragma unroll
    for (int k = 0; k < 60; ++k) acc3 += Z2p[(size_t)t * 64 + k] * w3p[k];
    out[(size_t)g * 32 + t] = acc3;
  }
}

extern "C" void kernel_launch(void* const* d_in, const int* in_sizes, int n_in,
                              void* d_out, int out_size, void* d_ws, size_t ws_size,
                              hipStream_t stream) {
  (void)in_sizes; (void)n_in; (void)out_size; (void)ws_size;
  const float* x1  = (const float*)d_in[0];
  const int*   ei1 = (const int*)d_in[1];
  const float* ea1 = (const float*)d_in[2];
  const float* x2  = (const float*)d_in[3];
  const int*   ei2 = (const int*)d_in[4];
  const float* ea2 = (const float*)d_in[5];
  const float* W1  = (const float*)d_in[6];
  const float* b1  = (const float*)d_in[7];
  const float* W4  = (const float*)d_in[8];
  const float* b4  = (const float*)d_in[9];
  const float* Wc1 = (const float*)d_in[10];
  const float* bc1 = (const float*)d_in[11];
  const float* Wc2 = (const float*)d_in[12];
  const float* bc2 = (const float*)d_in[13];
  const float* Wc3 = (const float*)d_in[14];
  const float* bc3 = (const float*)d_in[15];

  char* ws = (char*)d_ws;
  float* dinv  = (float*)(ws + OFF_DINV);
  short* arena = (short*)(ws + OFF_ARENA);
  short* WbT   = (short*)(ws + OFF_WBT);
  short* Wc1bT = (short*)(ws + OFF_WC1BT);
  short* W4bT  = (short*)(ws + OFF_W4BT);
  short* Lb    = (short*)(ws + OFF_LB);
  float* Y     = (float*)(ws + OFF_Y);
  unsigned short* meta = (unsigned short*)(ws + OFF_META);
  float* we    = (float*)(ws + OFF_WE);
  unsigned* bcnt = (unsigned*)(ws + OFF_BCNT);
  unsigned* bst  = (unsigned*)(ws + OFF_BST);
  float* out   = (float*)d_out;

  // L1: deg -> dinv + edge bucketing by d-tile + WbT conversion
  k_prep<<<344, 256, 0, stream>>>(ei1, ea1, ei2, ea2, W1, WbT, dinv,
                                  meta, we, bcnt, bst);
  // L2: bucketed Laplacian build || gemm1 (prefetched) || Wc1bT/W4bT tail
  k_build_gemm1<<<1814, 256, 0, stream>>>(meta, we, bcnt, bst, dinv, Lb,
                                          x1, x2, WbT, Wc1, W4, Y, arena,
                                          Wc1bT, W4bT);
  // L3: per-graph mega-block, 512 threads, reg-cached L across phases
  k_mega<<<128, NTHR, 0, stream>>>(Lb, arena, Y, W4bT, Wc1bT,
                                   b1, b4, bc1, Wc2, bc2, Wc3, bc3, out);
}

// Round 9
// 195.248 us; speedup vs baseline: 1.0682x; 1.0682x over previous
//
#include <hip/hip_runtime.h>
#include <hip/hip_bf16.h>

#define NN 268
#define NE 8192
#define KP 288   // padded node dim (268 -> 288)

typedef short short8 __attribute__((ext_vector_type(8)));   // 8 bf16 = 4 VGPR
typedef short short4v __attribute__((ext_vector_type(4)));  // 4 bf16 = 8B
typedef float f32x4 __attribute__((ext_vector_type(4)));

__device__ __forceinline__ short f2bf(float f) {
  __hip_bfloat16 h = __float2bfloat16(f);
  return *reinterpret_cast<short*>(&h);
}

// ---------------------------------------------------------------------------
// Workspace (bytes). Peak 62,135,296.
//   OFF_DINV  dinv  f32 [128][272]           139,264
//   OFF_ARENA Y2t   bf16[128][64][288]     4,718,592  (gemm1 out, megaA in)
//   OFF_WBT   WbT   bf16[192][288]           110,592
//   OFF_WC1BT Wc1bT bf16[112][288]            64,512
//   OFF_W4BT  W4bT  bf16[96][64]              12,288
//   OFF_LB    Lb    bf16[128][272][288]   20,054,016
//   OFF_Y     Y     f32 [128][268][192]   26,345,472
//   OFF_META/WE/BCNT/BST: bucketed edges (prep out, build in)
//   OFF_H1G   H1G   bf16[128][268][64]     4,390,912  (megaA out, megaB in)
// Round-9: mega split by FEATURE dim into megaA (256 blocks, P0-P2) +
// megaB (256 blocks, P3-P6+cls) — full-machine occupancy for the cheb chain.
// The only cross-f contraction (P3, K=64 over f) crosses the launch boundary
// via H1G. Arithmetic sequence identical to R8 (absmax must not move).
// ---------------------------------------------------------------------------
#define OFF_DINV  0
#define OFF_ARENA 139264
#define ARENA_SLAB_S 18432   // shorts per graph: Y2t [64][288]
#define OFF_WBT   4857856
#define OFF_WC1BT 4968448
#define OFF_W4BT  5032960
#define OFF_LB    5045248
#define OFF_Y     25099264
#define OFF_META  51444736
#define OFF_WE    53541888
#define OFF_BCNT  57736192
#define OFF_BST   57740288
#define OFF_H1G   57744384

// ---------------------------------------------------------------------------
// K1: prep (R8 verbatim). 344 blocks: degree+bucketing | WbT conversion.
// ---------------------------------------------------------------------------
__global__ __launch_bounds__(256) void k_prep(
    const int* __restrict__ ei1, const float* __restrict__ ea1,
    const int* __restrict__ ei2, const float* __restrict__ ea2,
    const float* __restrict__ W1, short* __restrict__ WbT,
    float* __restrict__ dinv, unsigned short* __restrict__ meta,
    float* __restrict__ we, unsigned* __restrict__ bcnt,
    unsigned* __restrict__ bst) {
  int t = threadIdx.x;
  int b = blockIdx.x;
  if (b < 128) {
    int g = b;
    const int* ei = (g < 64) ? (ei1 + (size_t)g * 2 * NE) : (ei2 + (size_t)(g - 64) * 2 * NE);
    const float* ea = (g < 64) ? (ea1 + (size_t)g * NE) : (ea2 + (size_t)(g - 64) * NE);
    __shared__ unsigned degL[NN];
    __shared__ unsigned bc[8], bs[8], bcur[8];
    for (int n = t; n < NN; n += 256) degL[n] = 0u;
    if (t < 8) bc[t] = 0u;
    __syncthreads();
#pragma unroll 4
    for (int e = t; e < NE; e += 256) {       // scan 1: degree + histogram
      int s = ei[e], d = ei[NE + e];
      float w = ea[e];
      if (s != d) {
        atomicAdd(&degL[s], (unsigned)lrintf(w * 1048576.f));
        atomicAdd(&bc[d / 34], 1u);
      }
    }
    __syncthreads();
    for (int n = t; n < 272; n += 256) {
      float r = 0.f;
      if (n < NN) {
        unsigned v = degL[n];
        if (v) r = rsqrtf((float)v * (1.f / 1048576.f));
      }
      dinv[(size_t)g * 272 + n] = r;
    }
    if (t == 0) {                             // prefix
      unsigned run = (unsigned)g * NE;
#pragma unroll
      for (int k = 0; k < 8; ++k) { bs[k] = run; run += bc[k]; }
    }
    __syncthreads();
    if (t < 8) {
      bcnt[g * 8 + t] = bc[t];
      bst[g * 8 + t] = bs[t];
      bcur[t] = bs[t];
    }
    __syncthreads();
#pragma unroll 4
    for (int e = t; e < NE; e += 256) {       // scan 2: scatter
      int s = ei[e], d = ei[NE + e];
      float w = ea[e];
      if (s != d) {
        int bk = d / 34;
        unsigned pos = atomicAdd(&bcur[bk], 1u);
        meta[pos] = (unsigned short)(((d - bk * 34) << 9) | s);
        we[pos] = w;
      }
    }
  } else {
    int idx = (b - 128) * 256 + t;  // 0..55295 = 192*288
    int n = idx / KP, kp = idx - n * KP;
    int kb = n >> 6, j = n & 63;
    float v = (kp < 268) ? W1[((size_t)kb * 268 + kp) * 64 + j] : 0.f;
    WbT[idx] = f2bf(v);
  }
}

// ---------------------------------------------------------------------------
// K2: fused Laplacian build + gemm1 + Wc1bT/W4bT tail (R8 verbatim).
// ---------------------------------------------------------------------------
__global__ __launch_bounds__(256) void k_build_gemm1(
    const unsigned short* __restrict__ meta, const float* __restrict__ we,
    const unsigned* __restrict__ bcnt, const unsigned* __restrict__ bst,
    const float* __restrict__ dinv_all, short* __restrict__ Lb,
    const float* __restrict__ x1, const float* __restrict__ x2,
    const short* __restrict__ WbT, const float* __restrict__ Wc1,
    const float* __restrict__ W4, float* __restrict__ Y,
    short* __restrict__ Y2t, short* __restrict__ Wc1bT,
    short* __restrict__ W4bT) {
  __shared__ __align__(16) char smem[34 * 288 * 4 + 272 * 4];  // 40,256 B
  int t = threadIdx.x;
  int bx = blockIdx.x;
  if (bx < 640) {
    // ===================== gemm1 (MFMA, A/B prefetched) ====================
    int xcd = bx & 7, rest = bx >> 3;       // rest 0..79
    int g = xcd + 8 * (rest / 5);           // graph on XCD g&7
    int m0 = (rest % 5) * 64;
    const float* A32 = (g < 64) ? (x1 + (size_t)g * NN * 268)
                                : (x2 + (size_t)(g - 64) * NN * 268);
    float* Yg = Y + (size_t)g * NN * 192;
    short* Y2tg = Y2t + (size_t)g * ARENA_SLAB_S;
    short (*As)[40] = (short(*)[40])smem;                     //  5,120 B
    short (*Bs)[40] = (short(*)[40])(smem + 5120);            // 15,360 B
    int w = t >> 6, lane = t & 63;
    int quad = lane >> 4, l16 = lane & 15;
    int mh = w & 1, nh = w >> 1;
    f32x4 acc[2][6];
#pragma unroll
    for (int mi = 0; mi < 2; ++mi)
#pragma unroll
      for (int ni = 0; ni < 6; ++ni) acc[mi][ni] = (f32x4){0.f, 0.f, 0.f, 0.f};

    int sr = t >> 2, sko = (t & 3) * 8;
    float4 pva, pvb;
    short8 pB[3];
    auto loadA = [&](int K0) {
      int row = m0 + sr, k = K0 + sko;
      pva = make_float4(0.f, 0.f, 0.f, 0.f); pvb = pva;
      if (row < NN && k < 268) pva = *(const float4*)(A32 + (size_t)row * 268 + k);
      if (row < NN && k + 4 < 268) pvb = *(const float4*)(A32 + (size_t)row * 268 + k + 4);
    };
    auto loadB = [&](int K0) {
#pragma unroll
      for (int i = 0; i < 3; ++i)
        pB[i] = *(const short8*)(WbT + (size_t)(sr + i * 64) * KP + K0 + sko);
    };
    loadA(0); loadB(0);
    for (int k0 = 0; k0 < KP; k0 += 32) {
      {
        short8 s;
        const float* fa = (const float*)&pva;
        const float* fb = (const float*)&pvb;
#pragma unroll
        for (int j = 0; j < 4; ++j) { s[j] = f2bf(fa[j]); s[4 + j] = f2bf(fb[j]); }
        *(short8*)(&As[sr][sko]) = s;
      }
#pragma unroll
      for (int i = 0; i < 3; ++i)
        *(short8*)(&Bs[sr + i * 64][sko]) = pB[i];
      __syncthreads();
      if (k0 + 32 < KP) { loadA(k0 + 32); loadB(k0 + 32); }  // hides under MFMA
      short8 af[2], bfr[6];
#pragma unroll
      for (int mi = 0; mi < 2; ++mi)
        af[mi] = *(const short8*)(&As[(mh * 2 + mi) * 16 + l16][quad * 8]);
#pragma unroll
      for (int ni = 0; ni < 6; ++ni)
        bfr[ni] = *(const short8*)(&Bs[(nh * 6 + ni) * 16 + l16][quad * 8]);
#pragma unroll
      for (int mi = 0; mi < 2; ++mi)
#pragma unroll
        for (int ni = 0; ni < 6; ++ni)
          acc[mi][ni] = __builtin_amdgcn_mfma_f32_16x16x32_bf16(af[mi], bfr[ni], acc[mi][ni], 0, 0, 0);
      __syncthreads();
    }
    // C/D: col = lane&15, row = quad*4 + reg
#pragma unroll
    for (int mi = 0; mi < 2; ++mi) {
      int rbase = m0 + (mh * 2 + mi) * 16 + quad * 4;
#pragma unroll
      for (int reg = 0; reg < 4; ++reg) {
        int row = rbase + reg;
        if (row < NN) {
#pragma unroll
          for (int ni = 0; ni < 6; ++ni) {
            int col = (nh * 6 + ni) * 16 + l16;
            Yg[(size_t)row * 192 + col] = acc[mi][ni][reg];
          }
        }
      }
      if (rbase < NN) {  // rbase % 4 == 0, never straddles 268
#pragma unroll
        for (int ni = 0; ni < 6; ++ni) {
          int col = (nh * 6 + ni) * 16 + l16;
          if (col >= 128) {
            short4v p;
#pragma unroll
            for (int reg = 0; reg < 4; ++reg) p[reg] = f2bf(acc[mi][ni][reg]);
            *(short4v*)(Y2tg + (size_t)(col - 128) * KP + rbase) = p;
          }
        }
      }
    }
  } else if (bx < 1664) {
    // ============ Laplacian build from buckets (8x less scanning) ==========
    int l = bx - 640;                // 0..1023 = 8 xcd * 16 g * 8 tiles
    int xcd = l & 7, rest = l >> 3;  // rest 0..127
    int g = xcd + 8 * (rest & 15);
    int tile = rest >> 4;            // 0..7
    int r0 = tile * 34;
    int* LrowI = (int*)smem;                      // 34*288 ints = 39,168 B
    float* dv = (float*)(smem + 39168);           // 272 floats
    for (int i = t; i < 34 * 288; i += 256) LrowI[i] = 0;
    for (int i = t; i < 272; i += 256) dv[i] = dinv_all[(size_t)g * 272 + i];
    __syncthreads();
    unsigned n = bcnt[g * 8 + tile];
    unsigned base = bst[g * 8 + tile];
    for (unsigned i = t; i < n; i += 256) {
      unsigned m = meta[base + i];
      float w = we[base + i];
      int dl = m >> 9, s = m & 511;
      atomicAdd(&LrowI[dl * 288 + s],
                (int)lrintf(-dv[s] * w * dv[r0 + dl] * 16777216.f));  // ds_add
    }
    __syncthreads();
    short* Lbg = Lb + (size_t)g * 272 * KP + (size_t)r0 * KP;
    for (int i = t; i < 34 * 288; i += 256)
      Lbg[i] = f2bf((float)LrowI[i] * (1.f / 16777216.f));
  } else {
    // ===================== Wc1bT / W4bT tail (megaB inputs) ================
    int idx = (bx - 1664) * 256 + t;  // 0..38399
    if (idx < 112 * KP) {
      int n = idx / KP, k = idx - n * KP;
      float v = (n < 100 && k < 268) ? Wc1[(size_t)k * 100 + n] : 0.f;
      Wc1bT[idx] = f2bf(v);
    } else {
      int i4 = idx - 112 * KP;       // 0..6143
      int n = i4 >> 6, k = i4 & 63;  // n in [0,96), k in [0,64)
      W4bT[i4] = f2bf(W4[(((size_t)(n >> 5)) * 64 + k) * 32 + (n & 31)]);
    }
  }
}

// ---------------------------------------------------------------------------
// Shared mega helpers (R8-verified): L fragment hoist + LDS-B MFMA body.
// ---------------------------------------------------------------------------
#define SP 296
#define NW 8
#define NTHR 512

__device__ __forceinline__ void load_a9(const short* __restrict__ Lbg,
                                        int mt, int l16, int quad, short8* a9) {
  const short* Arow = Lbg + (size_t)(mt * 16 + l16) * KP + quad * 8;
#pragma unroll
  for (int k = 0; k < 9; ++k) a9[k] = *(const short8*)(Arow + k * 32);
}

template <int NTN>
__device__ __forceinline__ void cheb_mm_pre(const short8* a9,
                                            const char* B0, int l16, int quad,
                                            f32x4* acc) {
#pragma unroll
  for (int k = 0; k < 9; ++k) {
#pragma unroll
    for (int nt = 0; nt < NTN; ++nt) {
      short8 bf = *(const short8*)(B0 +
          ((size_t)(nt * 16 + l16) * SP + k * 32 + quad * 8) * 2);
      acc[nt] = __builtin_amdgcn_mfma_f32_16x16x32_bf16(a9[k], bf, acc[nt], 0, 0, 0);
    }
  }
}

// ---------------------------------------------------------------------------
// K3: megaA — P0/P1/P2 split by feature half. 256 blocks (2/graph), 512 thr.
// Block (g, h) owns features f = h*32 .. h*32+32.
//   P0: Y2t rows [h*32, h*32+32) -> LDS (pad cols >=268 zeroed)
//   P1: Ut[f][s]  = bf16(Y1[s][f] + 2*(L@Y2)[s][f])   (LDS, own f only)
//   P2: H1[d][f]  = relu(Y0-Y2+(L@Ut)[d][f]+b1[f]) -> H1G global bf16
// LDS 37,888 B. L fragments hoisted to regs (R8 technique).
// ---------------------------------------------------------------------------
#define A_Y2H 0
#define A_UTH 18944
__global__ __launch_bounds__(NTHR, 1) void k_megaA(
    const short* __restrict__ Lb, const short* __restrict__ arena,
    const float* __restrict__ Y, const float* __restrict__ b1,
    short* __restrict__ H1G) {
  __shared__ __align__(16) char sm[37888];
  int b = blockIdx.x;
  int xcd = b & 7, idx = b >> 3;
  int g = xcd + 8 * (idx & 15);
  int h = idx >> 4;                    // feature half 0/1
  int t = threadIdx.x;
  int w = t >> 6, lane = t & 63;
  int quad = lane >> 4, l16 = lane & 15;
  const short* Lbg = Lb + (size_t)g * 272 * KP;
  const short* Y2tg = arena + (size_t)g * ARENA_SLAB_S + (size_t)h * 32 * KP;
  const float* Yg = Y + (size_t)g * NN * 192;
  short* H1gg = H1G + (size_t)g * 268 * 64;

  short8 aL0[9], aL1[9], aL2[9];
  load_a9(Lbg, w, l16, quad, aL0);
  load_a9(Lbg, w + 8, l16, quad, aL1);
  if (w == 0) load_a9(Lbg, 16, l16, quad, aL2);

  // P0: stage own 32 Y2t rows; cols >=268 zeroed (poison-safe)
  for (int i = t; i < 32 * 37; i += NTHR) {
    int r = i / 37, c = (i - r * 37) * 8;
    short8 v = {0, 0, 0, 0, 0, 0, 0, 0};
    if (c < 264) {
      v = *(const short8*)(Y2tg + (size_t)r * KP + c);
    } else if (c == 264) {
      v = *(const short8*)(Y2tg + (size_t)r * KP + 264);
      v[4] = 0; v[5] = 0; v[6] = 0; v[7] = 0;
    }
    *(short8*)(sm + A_Y2H + ((size_t)r * SP + c) * 2) = v;
  }
  for (int i = t; i < 32 * 20; i += NTHR) {  // zero Ut K-pad cols 268..288
    int f = i / 20, d = 268 + (i - f * 20);
    *(short*)(sm + A_UTH + ((size_t)f * SP + d) * 2) = 0;
  }
  __syncthreads();

  // P1: Ut[f_loc][d] = bf16(Y1[d][f_glob] + 2*(L@Y2)[d][f_glob])
  {
    auto body = [&](int mt, const short8* a9) {
      int dbase = mt * 16 + quad * 4;
      float yr[2][4];
      if (dbase < NN) {
#pragma unroll
        for (int nt = 0; nt < 2; ++nt)
#pragma unroll
          for (int reg = 0; reg < 4; ++reg)
            yr[nt][reg] = Yg[(size_t)(dbase + reg) * 192 + 64 + h * 32 + nt * 16 + l16];
      }
      f32x4 acc[2];
#pragma unroll
      for (int nt = 0; nt < 2; ++nt) acc[nt] = (f32x4){0.f, 0.f, 0.f, 0.f};
      cheb_mm_pre<2>(a9, sm + A_Y2H, l16, quad, acc);
      if (dbase < NN) {
#pragma unroll
        for (int nt = 0; nt < 2; ++nt) {
          int f_loc = nt * 16 + l16;
          short4v p;
#pragma unroll
          for (int reg = 0; reg < 4; ++reg)
            p[reg] = f2bf(yr[nt][reg] + 2.f * acc[nt][reg]);
          *(short4v*)(sm + A_UTH + ((size_t)f_loc * SP + dbase) * 2) = p;
        }
      }
    };
    body(w, aL0); body(w + 8, aL1); if (w == 0) body(16, aL2);
  }
  __syncthreads();

  // P2: H1[d][f_glob] = relu(Y0 - Y2 + (L@Ut) + b1) -> H1G global
  {
    auto body = [&](int mt, const short8* a9) {
      int dbase = mt * 16 + quad * 4;
      float yr0[2][4], yr2[2][4];
      if (dbase < NN) {
#pragma unroll
        for (int nt = 0; nt < 2; ++nt)
#pragma unroll
          for (int reg = 0; reg < 4; ++reg) {
            int fg = h * 32 + nt * 16 + l16;
            yr0[nt][reg] = Yg[(size_t)(dbase + reg) * 192 + fg];
            yr2[nt][reg] = Yg[(size_t)(dbase + reg) * 192 + 128 + fg];
          }
      }
      f32x4 acc[2];
#pragma unroll
      for (int nt = 0; nt < 2; ++nt) acc[nt] = (f32x4){0.f, 0.f, 0.f, 0.f};
      cheb_mm_pre<2>(a9, sm + A_UTH, l16, quad, acc);
      if (dbase < NN) {
#pragma unroll
        for (int nt = 0; nt < 2; ++nt) {
          int fg = h * 32 + nt * 16 + l16;
          float bb = b1[fg];
#pragma unroll
          for (int reg = 0; reg < 4; ++reg) {
            int d = dbase + reg;
            float v = yr0[nt][reg] - yr2[nt][reg] + acc[nt][reg] + bb;
            H1gg[(size_t)d * 64 + fg] = f2bf(fmaxf(v, 0.f));
          }
        }
      }
    };
    body(w, aL0); body(w + 8, aL1); if (w == 0) body(16, aL2);
  }
}

// ---------------------------------------------------------------------------
// K4: megaB — P3..P6+cls split by output-feature 16-group. 256 blocks
// (2/graph), 512 thr. Block (g,h) owns f = h*16 .. h*16+16 of the 32.
//   stage: H1s [272][72] (full, from H1G; rows>=268 zero), W4s [96][72]
//   P3: its 3 c-tiles {h,2+h,4+h}*16: Yb0T/Yb1T/Yb2T f32 LDS + YbB bf16
//   P4: Ut2[f][s] = bf16(Yb1 + 2*L@Yb2)       P5: H2 = relu(Yb0-Yb2+L@Ut2+b4)
//   P6: classifier rows f (L1 MFMA K=288, L2 reg-tiled, L3 dot) -> out
// LDS 114,688 B; residuals stay f32 in LDS (same values old code read
// from Yg) -> arithmetic identical.
// ---------------------------------------------------------------------------
#define B_H1S 0
#define B_W4S 39168
#define B_YB0 52992
#define B_YB1 70400
#define B_YB2 87808
#define B_YBB 105216
#define B_UT2 0
#define B_H2T 9472
#define B_Z1  18944
#define B_W2S 26368
#define B_Z2  52992      // overlays YB0; used only in P6 (after YB0 dead)
#define B_W3S 57088
__global__ __launch_bounds__(NTHR, 1) void k_megaB(
    const short* __restrict__ Lb, const short* __restrict__ H1G,
    const short* __restrict__ W4bT, const short* __restrict__ Wc1bT,
    const float* __restrict__ b4, const float* __restrict__ bc1,
    const float* __restrict__ Wc2, const float* __restrict__ bc2,
    const float* __restrict__ Wc3, const float* __restrict__ bc3,
    float* __restrict__ out) {
  __shared__ __align__(16) char sm[114688];
  int b = blockIdx.x;
  int xcd = b & 7, idx = b >> 3;
  int g = xcd + 8 * (idx & 15);
  int h = idx >> 4;                    // output-feature 16-group 0/1
  int t = threadIdx.x;
  int w = t >> 6, lane = t & 63;
  int quad = lane >> 4, l16 = lane & 15;
  const short* Lbg = Lb + (size_t)g * 272 * KP;
  const short* H1gg = H1G + (size_t)g * 268 * 64;

  short8 aL0[9], aL1[9], aL2[9];
  load_a9(Lbg, w, l16, quad, aL0);
  load_a9(Lbg, w + 8, l16, quad, aL1);
  if (w == 0) load_a9(Lbg, 16, l16, quad, aL2);

  // stage H1s [272][72] from H1G (rows >=268 zero; col group 8 = pad zeros)
  for (int i = t; i < 272 * 9; i += NTHR) {
    int r = i / 9, cg = i - r * 9;
    short8 v = {0, 0, 0, 0, 0, 0, 0, 0};
    if (cg < 8 && r < 268) v = *(const short8*)(H1gg + (size_t)r * 64 + cg * 8);
    *(short8*)(sm + B_H1S + ((size_t)r * 72 + cg * 8) * 2) = v;
  }
  for (int i = t; i < 96 * 8; i += NTHR) {   // W4s [96][72]
    int r = i >> 3, ko = (i & 7) * 8;
    *(short8*)(sm + B_W4S + ((size_t)r * 72 + ko) * 2) =
        *(const short8*)(W4bT + r * 64 + ko);
  }
  for (int i = t; i < 16 * 20; i += NTHR) {  // zero YbB K-pad cols 268..288
    int f = i / 20, d = 268 + (i - f * 20);
    *(short*)(sm + B_YBB + ((size_t)f * SP + d) * 2) = 0;
  }
  __syncthreads();

  // P3: 3 own c-tiles x 17 d-tiles, K=64 over f
  for (int id = w; id < 51; id += NW) {
    int ci = id / 17, nt = id - ci * 17;     // ci 0..3 -> c-tile h + 2*ci
    int ct = h + 2 * ci;
    f32x4 a1 = (f32x4){0.f, 0.f, 0.f, 0.f};
#pragma unroll
    for (int kc = 0; kc < 2; ++kc) {
      short8 af = *(const short8*)(sm + B_W4S +
          ((size_t)(ct * 16 + l16) * 72 + kc * 32 + quad * 8) * 2);
      short8 bf = *(const short8*)(sm + B_H1S +
          ((size_t)(nt * 16 + l16) * 72 + kc * 32 + quad * 8) * 2);
      a1 = __builtin_amdgcn_mfma_f32_16x16x32_bf16(af, bf, a1, 0, 0, 0);
    }
    int d = nt * 16 + l16;
    if (d < NN) {
#pragma unroll
      for (int reg = 0; reg < 4; ++reg) {
        int fl = quad * 4 + reg;             // local row in the 16-tile
        float a = a1[reg];
        if (ci == 0) {
          *(float*)(sm + B_YB0 + ((size_t)fl * 272 + d) * 4) = a;
        } else if (ci == 1) {
          *(float*)(sm + B_YB1 + ((size_t)fl * 272 + d) * 4) = a;
        } else {
          *(float*)(sm + B_YB2 + ((size_t)fl * 272 + d) * 4) = a;
          *(short*)(sm + B_YBB + ((size_t)fl * SP + d) * 2) = f2bf(a);
        }
      }
    }
  }
  __syncthreads();

  // zero Ut2/H2T K-pad cols (regions overlay dead H1s; safe after barrier)
  for (int i = t; i < 16 * 20; i += NTHR) {
    int f = i / 20, d = 268 + (i - f * 20);
    *(short*)(sm + B_UT2 + ((size_t)f * SP + d) * 2) = 0;
    *(short*)(sm + B_H2T + ((size_t)f * SP + d) * 2) = 0;
  }

  // P4: Ut2[f][d] = bf16(Yb1[d][f] + 2*(L@Yb2)[d][f])
  {
    auto body = [&](int mt, const short8* a9) {
      int dbase = mt * 16 + quad * 4;
      float yr[4];
      if (dbase < NN) {
#pragma unroll
        for (int reg = 0; reg < 4; ++reg)
          yr[reg] = *(const float*)(sm + B_YB1 + ((size_t)l16 * 272 + dbase + reg) * 4);
      }
      f32x4 acc1 = (f32x4){0.f, 0.f, 0.f, 0.f};
      cheb_mm_pre<1>(a9, sm + B_YBB, l16, quad, &acc1);
      if (dbase < NN) {
        short4v p;
#pragma unroll
        for (int reg = 0; reg < 4; ++reg)
          p[reg] = f2bf(yr[reg] + 2.f * acc1[reg]);
        *(short4v*)(sm + B_UT2 + ((size_t)l16 * SP + dbase) * 2) = p;
      }
    };
    body(w, aL0); body(w + 8, aL1); if (w == 0) body(16, aL2);
  }
  __syncthreads();

  // P5: H2T[f][d] = relu(Yb0 - Yb2 + (L@Ut2) + b4[f_glob])
  {
    float bb = b4[h * 16 + l16];
    auto body = [&](int mt, const short8* a9) {
      int dbase = mt * 16 + quad * 4;
      float yr0[4], yr2[4];
      if (dbase < NN) {
#pragma unroll
        for (int reg = 0; reg < 4; ++reg) {
          yr0[reg] = *(const float*)(sm + B_YB0 + ((size_t)l16 * 272 + dbase + reg) * 4);
          yr2[reg] = *(const float*)(sm + B_YB2 + ((size_t)l16 * 272 + dbase + reg) * 4);
        }
      }
      f32x4 acc1 = (f32x4){0.f, 0.f, 0.f, 0.f};
      cheb_mm_pre<1>(a9, sm + B_UT2, l16, quad, &acc1);
      if (dbase < NN) {
        short4v p;
#pragma unroll
        for (int reg = 0; reg < 4; ++reg) {
          float v = yr0[reg] - yr2[reg] + acc1[reg] + bb;
          p[reg] = f2bf(fmaxf(v, 0.f));
        }
        *(short4v*)(sm + B_H2T + ((size_t)l16 * SP + dbase) * 2) = p;
      }
    };
    body(w, aL0); body(w + 8, aL1); if (w == 0) body(16, aL2);
  }
  __syncthreads();

  // P6-L1: Z1[f][col] MFMA (A = H2T rows f, 1 m-tile; B = Wc1bT, K=288)
  for (int id = w; id < 7; id += NW) {
    f32x4 a1 = (f32x4){0.f, 0.f, 0.f, 0.f};
#pragma unroll
    for (int k = 0; k < 9; ++k) {
      short8 af = *(const short8*)(sm + B_H2T +
          ((size_t)l16 * SP + k * 32 + quad * 8) * 2);
      short8 bf = *(const short8*)(Wc1bT + (size_t)(id * 16 + l16) * KP + k * 32 + quad * 8);
      a1 = __builtin_amdgcn_mfma_f32_16x16x32_bf16(af, bf, a1, 0, 0, 0);
    }
    int col = id * 16 + l16;
    if (col < 100) {
      float bb = bc1[col];
#pragma unroll
      for (int reg = 0; reg < 4; ++reg)
        *(float*)(sm + B_Z1 + ((size_t)(quad * 4 + reg) * 116 + col) * 4) =
            fmaxf(a1[reg] + bb, 0.f);
    }
  }
  for (int i = t; i < 100 * 64; i += NTHR) { // stage W2s [100][64]
    int rr = i >> 6, c = i & 63;
    *(float*)(sm + B_W2S + ((size_t)rr * 64 + c) * 4) =
        (c < 60) ? Wc2[(size_t)rr * 60 + c] : 0.f;
  }
  if (t < 64) *(float*)(sm + B_W3S + (size_t)t * 4) = (t < 60) ? Wc3[t] : 0.f;
  __syncthreads();
  if (t < 64) {                              // L2: 16 rows x 64 cols
    int r2 = (t >> 3) * 2;
    int c8 = (t & 7) * 8;
    float a2[2][8];
#pragma unroll
    for (int i = 0; i < 2; ++i)
#pragma unroll
      for (int j = 0; j < 8; ++j) a2[i][j] = 0.f;
    const float* Z1p = (const float*)(sm + B_Z1);
    const float* W2p = (const float*)(sm + B_W2S);
#pragma unroll 4
    for (int k = 0; k < 100; ++k) {
      float x0 = Z1p[(size_t)r2 * 116 + k], x1 = Z1p[(size_t)(r2 + 1) * 116 + k];
      float4 wA = *(const float4*)(W2p + (size_t)k * 64 + c8);
      float4 wB = *(const float4*)(W2p + (size_t)k * 64 + c8 + 4);
      float wv[8] = {wA.x, wA.y, wA.z, wA.w, wB.x, wB.y, wB.z, wB.w};
#pragma unroll
      for (int j = 0; j < 8; ++j) { a2[0][j] += x0 * wv[j]; a2[1][j] += x1 * wv[j]; }
    }
    float* Z2p = (float*)(sm + B_Z2);
#pragma unroll
    for (int j = 0; j < 8; ++j) {
      int c = c8 + j;
      float bb = (c < 60) ? bc2[c] : 0.f;
      Z2p[(size_t)r2 * 64 + c] = fmaxf(a2[0][j] + bb, 0.f);
      Z2p[(size_t)(r2 + 1) * 64 + c] = fmaxf(a2[1][j] + bb, 0.f);
    }
  }
  __syncthreads();
  if (t < 16) {                              // L3: out = Z2 . Wc3 + bc3
    const float* Z2p = (const float*)(sm + B_Z2);
    const float* w3p = (const float*)(sm + B_W3S);
    float acc3 = bc3[0];
#pragma unroll
    for (int k = 0; k < 60; ++k) acc3 += Z2p[(size_t)t * 64 + k] * w3p[k];
    out[(size_t)g * 32 + h * 16 + t] = acc3;
  }
}

extern "C" void kernel_launch(void* const* d_in, const int* in_sizes, int n_in,
                              void* d_out, int out_size, void* d_ws, size_t ws_size,
                              hipStream_t stream) {
  (void)in_sizes; (void)n_in; (void)out_size; (void)ws_size;
  const float* x1  = (const float*)d_in[0];
  const int*   ei1 = (const int*)d_in[1];
  const float* ea1 = (const float*)d_in[2];
  const float* x2  = (const float*)d_in[3];
  const int*   ei2 = (const int*)d_in[4];
  const float* ea2 = (const float*)d_in[5];
  const float* W1  = (const float*)d_in[6];
  const float* b1  = (const float*)d_in[7];
  const float* W4  = (const float*)d_in[8];
  const float* b4  = (const float*)d_in[9];
  const float* Wc1 = (const float*)d_in[10];
  const float* bc1 = (const float*)d_in[11];
  const float* Wc2 = (const float*)d_in[12];
  const float* bc2 = (const float*)d_in[13];
  const float* Wc3 = (const float*)d_in[14];
  const float* bc3 = (const float*)d_in[15];

  char* ws = (char*)d_ws;
  float* dinv  = (float*)(ws + OFF_DINV);
  short* arena = (short*)(ws + OFF_ARENA);
  short* WbT   = (short*)(ws + OFF_WBT);
  short* Wc1bT = (short*)(ws + OFF_WC1BT);
  short* W4bT  = (short*)(ws + OFF_W4BT);
  short* Lb    = (short*)(ws + OFF_LB);
  float* Y     = (float*)(ws + OFF_Y);
  unsigned short* meta = (unsigned short*)(ws + OFF_META);
  float* we    = (float*)(ws + OFF_WE);
  unsigned* bcnt = (unsigned*)(ws + OFF_BCNT);
  unsigned* bst  = (unsigned*)(ws + OFF_BST);
  short* H1G   = (short*)(ws + OFF_H1G);
  float* out   = (float*)d_out;

  // L1: deg -> dinv + edge bucketing + WbT conversion
  k_prep<<<344, 256, 0, stream>>>(ei1, ea1, ei2, ea2, W1, WbT, dinv,
                                  meta, we, bcnt, bst);
  // L2: bucketed Laplacian build || gemm1 (prefetched) || Wc1bT/W4bT tail
  k_build_gemm1<<<1814, 256, 0, stream>>>(meta, we, bcnt, bst, dinv, Lb,
                                          x1, x2, WbT, Wc1, W4, Y, arena,
                                          Wc1bT, W4bT);
  // L3: megaA — P0-P2, feature-halved, 256 blocks (full machine)
  k_megaA<<<256, NTHR, 0, stream>>>(Lb, arena, Y, b1, H1G);
  // L4: megaB — P3-P6+cls, feature-16-split, 256 blocks (full machine)
  k_megaB<<<256, NTHR, 0, stream>>>(Lb, H1G, W4bT, Wc1bT,
                                    b4, bc1, Wc2, bc2, Wc3, bc3, out);
}

// Round 10
// 182.325 us; speedup vs baseline: 1.1439x; 1.0709x over previous
//
#include <hip/hip_runtime.h>
#include <hip/hip_bf16.h>

#define NN 268
#define NE 8192
#define KP 288   // padded node dim (268 -> 288)

typedef short short8 __attribute__((ext_vector_type(8)));   // 8 bf16 = 4 VGPR
typedef short short4v __attribute__((ext_vector_type(4)));  // 4 bf16 = 8B
typedef float f32x4 __attribute__((ext_vector_type(4)));

__device__ __forceinline__ short f2bf(float f) {
  __hip_bfloat16 h = __float2bfloat16(f);
  return *reinterpret_cast<short*>(&h);
}

// ---------------------------------------------------------------------------
// Workspace (bytes). Peak 55,835,648.
//   OFF_DINV  dinv  f32 [128][272]           139,264
//   OFF_ARENA Y2t   bf16[128][64][288]     4,718,592  (gemm1 out, megaA in)
//   OFF_WBT   WbT   bf16[192][288]           110,592  (prep out, gemm1 in)
//   OFF_WC1BT Wc1bT bf16[112][288]            64,512
//   OFF_W4BT  W4bT  bf16[96][64]              12,288
//   OFF_LB    Lb    bf16[128][272][288]   20,054,016
//   OFF_Y     Y     f32 [128][268][192]   26,345,472
//   OFF_H1G   H1G   bf16[128][268][64]     4,390,912  (megaA out, megaB in)
// Round-10: REVERT R8's edge bucketing (prep cost +33 us for <9 us build
// gain — counters r9: prep 41 us, 4.9% occupancy, uncoalesced u16 scatter).
// prep = deg + WbT only, at 1024 threads (8 serial edge iters, not 32).
// build = R7 full-scan (bit-identical Lb: int fixed-point accumulation is
// order-independent). megaA/megaB = R9 verbatim (passed).
// ---------------------------------------------------------------------------
#define OFF_DINV  0
#define OFF_ARENA 139264
#define ARENA_SLAB_S 18432   // shorts per graph: Y2t [64][288]
#define OFF_WBT   4857856
#define OFF_WC1BT 4968448
#define OFF_W4BT  5032960
#define OFF_LB    5045248
#define OFF_Y     25099264
#define OFF_H1G   51444736

// ---------------------------------------------------------------------------
// K1: prep, 182 blocks x 1024 threads.
//  [0,128):   per-graph degree -> dinv (1 edge scan, 8 iters/thread).
//  [128,182): WbT conversion (54*1024 = 55296 elements exactly).
// ---------------------------------------------------------------------------
__global__ __launch_bounds__(1024) void k_prep(
    const int* __restrict__ ei1, const float* __restrict__ ea1,
    const int* __restrict__ ei2, const float* __restrict__ ea2,
    const float* __restrict__ W1, short* __restrict__ WbT,
    float* __restrict__ dinv) {
  int t = threadIdx.x;
  int b = blockIdx.x;
  if (b < 128) {
    int g = b;
    const int* ei = (g < 64) ? (ei1 + (size_t)g * 2 * NE) : (ei2 + (size_t)(g - 64) * 2 * NE);
    const float* ea = (g < 64) ? (ea1 + (size_t)g * NE) : (ea2 + (size_t)(g - 64) * NE);
    __shared__ unsigned degL[NN];
    if (t < NN) degL[t] = 0u;
    __syncthreads();
#pragma unroll 4
    for (int e = t; e < NE; e += 1024) {
      int s = ei[e], d = ei[NE + e];
      float w = ea[e];
      if (s != d) atomicAdd(&degL[s], (unsigned)lrintf(w * 1048576.f));
    }
    __syncthreads();
    if (t < 272) {
      float r = 0.f;
      if (t < NN) {
        unsigned v = degL[t];
        if (v) r = rsqrtf((float)v * (1.f / 1048576.f));
      }
      dinv[(size_t)g * 272 + t] = r;
    }
  } else {
    int idx = (b - 128) * 1024 + t;  // 0..55295 = 192*288
    int n = idx / KP, kp = idx - n * KP;
    int kb = n >> 6, j = n & 63;
    float v = (kp < 268) ? W1[((size_t)kb * 268 + kp) * 64 + j] : 0.f;
    WbT[idx] = f2bf(v);
  }
}

// ---------------------------------------------------------------------------
// K2: fused Laplacian build + gemm1 + Wc1bT/W4bT tail (R7 verbatim, 49.0 us).
//  [0,640):     gemm1 (MFMA), WbT B, A/B register prefetch.
//  [640,1664):  Laplacian 34-row tiles, full edge scan.
//  [1664,1814): Wc1bT / W4bT conversion (megaB inputs).
// ---------------------------------------------------------------------------
__global__ __launch_bounds__(256) void k_build_gemm1(
    const int* __restrict__ ei1, const float* __restrict__ ea1,
    const int* __restrict__ ei2, const float* __restrict__ ea2,
    const float* __restrict__ dinv_all, short* __restrict__ Lb,
    const float* __restrict__ x1, const float* __restrict__ x2,
    const short* __restrict__ WbT, const float* __restrict__ Wc1,
    const float* __restrict__ W4, float* __restrict__ Y,
    short* __restrict__ Y2t, short* __restrict__ Wc1bT,
    short* __restrict__ W4bT) {
  __shared__ __align__(16) char smem[34 * 288 * 4 + 272 * 4];  // 40,256 B
  int t = threadIdx.x;
  int bx = blockIdx.x;
  if (bx < 640) {
    // ===================== gemm1 (MFMA, A/B prefetched) ====================
    int xcd = bx & 7, rest = bx >> 3;       // rest 0..79
    int g = xcd + 8 * (rest / 5);           // graph on XCD g&7
    int m0 = (rest % 5) * 64;
    const float* A32 = (g < 64) ? (x1 + (size_t)g * NN * 268)
                                : (x2 + (size_t)(g - 64) * NN * 268);
    float* Yg = Y + (size_t)g * NN * 192;
    short* Y2tg = Y2t + (size_t)g * ARENA_SLAB_S;
    short (*As)[40] = (short(*)[40])smem;                     //  5,120 B
    short (*Bs)[40] = (short(*)[40])(smem + 5120);            // 15,360 B
    int w = t >> 6, lane = t & 63;
    int quad = lane >> 4, l16 = lane & 15;
    int mh = w & 1, nh = w >> 1;
    f32x4 acc[2][6];
#pragma unroll
    for (int mi = 0; mi < 2; ++mi)
#pragma unroll
      for (int ni = 0; ni < 6; ++ni) acc[mi][ni] = (f32x4){0.f, 0.f, 0.f, 0.f};

    int sr = t >> 2, sko = (t & 3) * 8;
    float4 pva, pvb;
    short8 pB[3];
    auto loadA = [&](int K0) {
      int row = m0 + sr, k = K0 + sko;
      pva = make_float4(0.f, 0.f, 0.f, 0.f); pvb = pva;
      if (row < NN && k < 268) pva = *(const float4*)(A32 + (size_t)row * 268 + k);
      if (row < NN && k + 4 < 268) pvb = *(const float4*)(A32 + (size_t)row * 268 + k + 4);
    };
    auto loadB = [&](int K0) {
#pragma unroll
      for (int i = 0; i < 3; ++i)
        pB[i] = *(const short8*)(WbT + (size_t)(sr + i * 64) * KP + K0 + sko);
    };
    loadA(0); loadB(0);
    for (int k0 = 0; k0 < KP; k0 += 32) {
      {
        short8 s;
        const float* fa = (const float*)&pva;
        const float* fb = (const float*)&pvb;
#pragma unroll
        for (int j = 0; j < 4; ++j) { s[j] = f2bf(fa[j]); s[4 + j] = f2bf(fb[j]); }
        *(short8*)(&As[sr][sko]) = s;
      }
#pragma unroll
      for (int i = 0; i < 3; ++i)
        *(short8*)(&Bs[sr + i * 64][sko]) = pB[i];
      __syncthreads();
      if (k0 + 32 < KP) { loadA(k0 + 32); loadB(k0 + 32); }  // hides under MFMA
      short8 af[2], bfr[6];
#pragma unroll
      for (int mi = 0; mi < 2; ++mi)
        af[mi] = *(const short8*)(&As[(mh * 2 + mi) * 16 + l16][quad * 8]);
#pragma unroll
      for (int ni = 0; ni < 6; ++ni)
        bfr[ni] = *(const short8*)(&Bs[(nh * 6 + ni) * 16 + l16][quad * 8]);
#pragma unroll
      for (int mi = 0; mi < 2; ++mi)
#pragma unroll
        for (int ni = 0; ni < 6; ++ni)
          acc[mi][ni] = __builtin_amdgcn_mfma_f32_16x16x32_bf16(af[mi], bfr[ni], acc[mi][ni], 0, 0, 0);
      __syncthreads();
    }
    // C/D: col = lane&15, row = quad*4 + reg
#pragma unroll
    for (int mi = 0; mi < 2; ++mi) {
      int rbase = m0 + (mh * 2 + mi) * 16 + quad * 4;
#pragma unroll
      for (int reg = 0; reg < 4; ++reg) {
        int row = rbase + reg;
        if (row < NN) {
#pragma unroll
          for (int ni = 0; ni < 6; ++ni) {
            int col = (nh * 6 + ni) * 16 + l16;
            Yg[(size_t)row * 192 + col] = acc[mi][ni][reg];
          }
        }
      }
      if (rbase < NN) {  // rbase % 4 == 0, never straddles 268
#pragma unroll
        for (int ni = 0; ni < 6; ++ni) {
          int col = (nh * 6 + ni) * 16 + l16;
          if (col >= 128) {
            short4v p;
#pragma unroll
            for (int reg = 0; reg < 4; ++reg) p[reg] = f2bf(acc[mi][ni][reg]);
            *(short4v*)(Y2tg + (size_t)(col - 128) * KP + rbase) = p;
          }
        }
      }
    }
  } else if (bx < 1664) {
    // ===================== Laplacian build (full scan) =====================
    int l = bx - 640;                // 0..1023 = 8 xcd * 16 g * 8 tiles
    int xcd = l & 7, rest = l >> 3;  // rest 0..127
    int g = xcd + 8 * (rest & 15);
    int tile = rest >> 4;            // 0..7
    int r0 = tile * 34;
    const int* ei = (g < 64) ? (ei1 + (size_t)g * 2 * NE) : (ei2 + (size_t)(g - 64) * 2 * NE);
    const float* ea = (g < 64) ? (ea1 + (size_t)g * NE) : (ea2 + (size_t)(g - 64) * NE);
    int* LrowI = (int*)smem;                      // 34*288 ints = 39,168 B
    float* dv = (float*)(smem + 39168);           // 272 floats
    for (int i = t; i < 34 * 288; i += 256) LrowI[i] = 0;
    for (int i = t; i < 272; i += 256) dv[i] = dinv_all[(size_t)g * 272 + i];
    __syncthreads();
#pragma unroll 8
    for (int e = t; e < NE; e += 256) {
      int d = ei[NE + e];
      int s = ei[e];
      float w = ea[e];
      if (d >= r0 && d < r0 + 34 && s != d) {
        atomicAdd(&LrowI[(d - r0) * 288 + s],
                  (int)lrintf(-dv[s] * w * dv[d] * 16777216.f));  // native ds_add
      }
    }
    __syncthreads();
    short* Lbg = Lb + (size_t)g * 272 * KP + (size_t)r0 * KP;
    for (int i = t; i < 34 * 288; i += 256)
      Lbg[i] = f2bf((float)LrowI[i] * (1.f / 16777216.f));
  } else {
    // ===================== Wc1bT / W4bT tail (megaB inputs) ================
    int idx = (bx - 1664) * 256 + t;  // 0..38399
    if (idx < 112 * KP) {
      int n = idx / KP, k = idx - n * KP;
      float v = (n < 100 && k < 268) ? Wc1[(size_t)k * 100 + n] : 0.f;
      Wc1bT[idx] = f2bf(v);
    } else {
      int i4 = idx - 112 * KP;       // 0..6143
      int n = i4 >> 6, k = i4 & 63;  // n in [0,96), k in [0,64)
      W4bT[i4] = f2bf(W4[(((size_t)(n >> 5)) * 64 + k) * 32 + (n & 31)]);
    }
  }
}

// ---------------------------------------------------------------------------
// Shared mega helpers (R8-verified): L fragment hoist + LDS-B MFMA body.
// ---------------------------------------------------------------------------
#define SP 296
#define NW 8
#define NTHR 512

__device__ __forceinline__ void load_a9(const short* __restrict__ Lbg,
                                        int mt, int l16, int quad, short8* a9) {
  const short* Arow = Lbg + (size_t)(mt * 16 + l16) * KP + quad * 8;
#pragma unroll
  for (int k = 0; k < 9; ++k) a9[k] = *(const short8*)(Arow + k * 32);
}

template <int NTN>
__device__ __forceinline__ void cheb_mm_pre(const short8* a9,
                                            const char* B0, int l16, int quad,
                                            f32x4* acc) {
#pragma unroll
  for (int k = 0; k < 9; ++k) {
#pragma unroll
    for (int nt = 0; nt < NTN; ++nt) {
      short8 bf = *(const short8*)(B0 +
          ((size_t)(nt * 16 + l16) * SP + k * 32 + quad * 8) * 2);
      acc[nt] = __builtin_amdgcn_mfma_f32_16x16x32_bf16(a9[k], bf, acc[nt], 0, 0, 0);
    }
  }
}

// ---------------------------------------------------------------------------
// K3: megaA (R9 verbatim) — P0/P1/P2 by feature half. 256 blocks, 512 thr.
// ---------------------------------------------------------------------------
#define A_Y2H 0
#define A_UTH 18944
__global__ __launch_bounds__(NTHR, 1) void k_megaA(
    const short* __restrict__ Lb, const short* __restrict__ arena,
    const float* __restrict__ Y, const float* __restrict__ b1,
    short* __restrict__ H1G) {
  __shared__ __align__(16) char sm[37888];
  int b = blockIdx.x;
  int xcd = b & 7, idx = b >> 3;
  int g = xcd + 8 * (idx & 15);
  int h = idx >> 4;                    // feature half 0/1
  int t = threadIdx.x;
  int w = t >> 6, lane = t & 63;
  int quad = lane >> 4, l16 = lane & 15;
  const short* Lbg = Lb + (size_t)g * 272 * KP;
  const short* Y2tg = arena + (size_t)g * ARENA_SLAB_S + (size_t)h * 32 * KP;
  const float* Yg = Y + (size_t)g * NN * 192;
  short* H1gg = H1G + (size_t)g * 268 * 64;

  short8 aL0[9], aL1[9], aL2[9];
  load_a9(Lbg, w, l16, quad, aL0);
  load_a9(Lbg, w + 8, l16, quad, aL1);
  if (w == 0) load_a9(Lbg, 16, l16, quad, aL2);

  // P0: stage own 32 Y2t rows; cols >=268 zeroed (poison-safe)
  for (int i = t; i < 32 * 37; i += NTHR) {
    int r = i / 37, c = (i - r * 37) * 8;
    short8 v = {0, 0, 0, 0, 0, 0, 0, 0};
    if (c < 264) {
      v = *(const short8*)(Y2tg + (size_t)r * KP + c);
    } else if (c == 264) {
      v = *(const short8*)(Y2tg + (size_t)r * KP + 264);
      v[4] = 0; v[5] = 0; v[6] = 0; v[7] = 0;
    }
    *(short8*)(sm + A_Y2H + ((size_t)r * SP + c) * 2) = v;
  }
  for (int i = t; i < 32 * 20; i += NTHR) {  // zero Ut K-pad cols 268..288
    int f = i / 20, d = 268 + (i - f * 20);
    *(short*)(sm + A_UTH + ((size_t)f * SP + d) * 2) = 0;
  }
  __syncthreads();

  // P1: Ut[f_loc][d] = bf16(Y1[d][f_glob] + 2*(L@Y2)[d][f_glob])
  {
    auto body = [&](int mt, const short8* a9) {
      int dbase = mt * 16 + quad * 4;
      float yr[2][4];
      if (dbase < NN) {
#pragma unroll
        for (int nt = 0; nt < 2; ++nt)
#pragma unroll
          for (int reg = 0; reg < 4; ++reg)
            yr[nt][reg] = Yg[(size_t)(dbase + reg) * 192 + 64 + h * 32 + nt * 16 + l16];
      }
      f32x4 acc[2];
#pragma unroll
      for (int nt = 0; nt < 2; ++nt) acc[nt] = (f32x4){0.f, 0.f, 0.f, 0.f};
      cheb_mm_pre<2>(a9, sm + A_Y2H, l16, quad, acc);
      if (dbase < NN) {
#pragma unroll
        for (int nt = 0; nt < 2; ++nt) {
          int f_loc = nt * 16 + l16;
          short4v p;
#pragma unroll
          for (int reg = 0; reg < 4; ++reg)
            p[reg] = f2bf(yr[nt][reg] + 2.f * acc[nt][reg]);
          *(short4v*)(sm + A_UTH + ((size_t)f_loc * SP + dbase) * 2) = p;
        }
      }
    };
    body(w, aL0); body(w + 8, aL1); if (w == 0) body(16, aL2);
  }
  __syncthreads();

  // P2: H1[d][f_glob] = relu(Y0 - Y2 + (L@Ut) + b1) -> H1G global
  {
    auto body = [&](int mt, const short8* a9) {
      int dbase = mt * 16 + quad * 4;
      float yr0[2][4], yr2[2][4];
      if (dbase < NN) {
#pragma unroll
        for (int nt = 0; nt < 2; ++nt)
#pragma unroll
          for (int reg = 0; reg < 4; ++reg) {
            int fg = h * 32 + nt * 16 + l16;
            yr0[nt][reg] = Yg[(size_t)(dbase + reg) * 192 + fg];
            yr2[nt][reg] = Yg[(size_t)(dbase + reg) * 192 + 128 + fg];
          }
      }
      f32x4 acc[2];
#pragma unroll
      for (int nt = 0; nt < 2; ++nt) acc[nt] = (f32x4){0.f, 0.f, 0.f, 0.f};
      cheb_mm_pre<2>(a9, sm + A_UTH, l16, quad, acc);
      if (dbase < NN) {
#pragma unroll
        for (int nt = 0; nt < 2; ++nt) {
          int fg = h * 32 + nt * 16 + l16;
          float bb = b1[fg];
#pragma unroll
          for (int reg = 0; reg < 4; ++reg) {
            int d = dbase + reg;
            float v = yr0[nt][reg] - yr2[nt][reg] + acc[nt][reg] + bb;
            H1gg[(size_t)d * 64 + fg] = f2bf(fmaxf(v, 0.f));
          }
        }
      }
    };
    body(w, aL0); body(w + 8, aL1); if (w == 0) body(16, aL2);
  }
}

// ---------------------------------------------------------------------------
// K4: megaB (R9 verbatim) — P3..P6+cls by output-feature 16-group.
// 256 blocks, 512 thr.
// ---------------------------------------------------------------------------
#define B_H1S 0
#define B_W4S 39168
#define B_YB0 52992
#define B_YB1 70400
#define B_YB2 87808
#define B_YBB 105216
#define B_UT2 0
#define B_H2T 9472
#define B_Z1  18944
#define B_W2S 26368
#define B_Z2  52992      // overlays YB0; used only in P6 (after YB0 dead)
#define B_W3S 57088
__global__ __launch_bounds__(NTHR, 1) void k_megaB(
    const short* __restrict__ Lb, const short* __restrict__ H1G,
    const short* __restrict__ W4bT, const short* __restrict__ Wc1bT,
    const float* __restrict__ b4, const float* __restrict__ bc1,
    const float* __restrict__ Wc2, const float* __restrict__ bc2,
    const float* __restrict__ Wc3, const float* __restrict__ bc3,
    float* __restrict__ out) {
  __shared__ __align__(16) char sm[114688];
  int b = blockIdx.x;
  int xcd = b & 7, idx = b >> 3;
  int g = xcd + 8 * (idx & 15);
  int h = idx >> 4;                    // output-feature 16-group 0/1
  int t = threadIdx.x;
  int w = t >> 6, lane = t & 63;
  int quad = lane >> 4, l16 = lane & 15;
  const short* Lbg = Lb + (size_t)g * 272 * KP;
  const short* H1gg = H1G + (size_t)g * 268 * 64;

  short8 aL0[9], aL1[9], aL2[9];
  load_a9(Lbg, w, l16, quad, aL0);
  load_a9(Lbg, w + 8, l16, quad, aL1);
  if (w == 0) load_a9(Lbg, 16, l16, quad, aL2);

  // stage H1s [272][72] from H1G (rows >=268 zero; col group 8 = pad zeros)
  for (int i = t; i < 272 * 9; i += NTHR) {
    int r = i / 9, cg = i - r * 9;
    short8 v = {0, 0, 0, 0, 0, 0, 0, 0};
    if (cg < 8 && r < 268) v = *(const short8*)(H1gg + (size_t)r * 64 + cg * 8);
    *(short8*)(sm + B_H1S + ((size_t)r * 72 + cg * 8) * 2) = v;
  }
  for (int i = t; i < 96 * 8; i += NTHR) {   // W4s [96][72]
    int r = i >> 3, ko = (i & 7) * 8;
    *(short8*)(sm + B_W4S + ((size_t)r * 72 + ko) * 2) =
        *(const short8*)(W4bT + r * 64 + ko);
  }
  for (int i = t; i < 16 * 20; i += NTHR) {  // zero YbB K-pad cols 268..288
    int f = i / 20, d = 268 + (i - f * 20);
    *(short*)(sm + B_YBB + ((size_t)f * SP + d) * 2) = 0;
  }
  __syncthreads();

  // P3: 3 own c-tiles x 17 d-tiles, K=64 over f
  for (int id = w; id < 51; id += NW) {
    int ci = id / 17, nt = id - ci * 17;     // ci 0..2 -> c-tile h + 2*ci
    int ct = h + 2 * ci;
    f32x4 a1 = (f32x4){0.f, 0.f, 0.f, 0.f};
#pragma unroll
    for (int kc = 0; kc < 2; ++kc) {
      short8 af = *(const short8*)(sm + B_W4S +
          ((size_t)(ct * 16 + l16) * 72 + kc * 32 + quad * 8) * 2);
      short8 bf = *(const short8*)(sm + B_H1S +
          ((size_t)(nt * 16 + l16) * 72 + kc * 32 + quad * 8) * 2);
      a1 = __builtin_amdgcn_mfma_f32_16x16x32_bf16(af, bf, a1, 0, 0, 0);
    }
    int d = nt * 16 + l16;
    if (d < NN) {
#pragma unroll
      for (int reg = 0; reg < 4; ++reg) {
        int fl = quad * 4 + reg;             // local row in the 16-tile
        float a = a1[reg];
        if (ci == 0) {
          *(float*)(sm + B_YB0 + ((size_t)fl * 272 + d) * 4) = a;
        } else if (ci == 1) {
          *(float*)(sm + B_YB1 + ((size_t)fl * 272 + d) * 4) = a;
        } else {
          *(float*)(sm + B_YB2 + ((size_t)fl * 272 + d) * 4) = a;
          *(short*)(sm + B_YBB + ((size_t)fl * SP + d) * 2) = f2bf(a);
        }
      }
    }
  }
  __syncthreads();

  // zero Ut2/H2T K-pad cols (regions overlay dead H1s; safe after barrier)
  for (int i = t; i < 16 * 20; i += NTHR) {
    int f = i / 20, d = 268 + (i - f * 20);
    *(short*)(sm + B_UT2 + ((size_t)f * SP + d) * 2) = 0;
    *(short*)(sm + B_H2T + ((size_t)f * SP + d) * 2) = 0;
  }

  // P4: Ut2[f][d] = bf16(Yb1[d][f] + 2*(L@Yb2)[d][f])
  {
    auto body = [&](int mt, const short8* a9) {
      int dbase = mt * 16 + quad * 4;
      float yr[4];
      if (dbase < NN) {
#pragma unroll
        for (int reg = 0; reg < 4; ++reg)
          yr[reg] = *(const float*)(sm + B_YB1 + ((size_t)l16 * 272 + dbase + reg) * 4);
      }
      f32x4 acc1 = (f32x4){0.f, 0.f, 0.f, 0.f};
      cheb_mm_pre<1>(a9, sm + B_YBB, l16, quad, &acc1);
      if (dbase < NN) {
        short4v p;
#pragma unroll
        for (int reg = 0; reg < 4; ++reg)
          p[reg] = f2bf(yr[reg] + 2.f * acc1[reg]);
        *(short4v*)(sm + B_UT2 + ((size_t)l16 * SP + dbase) * 2) = p;
      }
    };
    body(w, aL0); body(w + 8, aL1); if (w == 0) body(16, aL2);
  }
  __syncthreads();

  // P5: H2T[f][d] = relu(Yb0 - Yb2 + (L@Ut2) + b4[f_glob])
  {
    float bb = b4[h * 16 + l16];
    auto body = [&](int mt, const short8* a9) {
      int dbase = mt * 16 + quad * 4;
      float yr0[4], yr2[4];
      if (dbase < NN) {
#pragma unroll
        for (int reg = 0; reg < 4; ++reg) {
          yr0[reg] = *(const float*)(sm + B_YB0 + ((size_t)l16 * 272 + dbase + reg) * 4);
          yr2[reg] = *(const float*)(sm + B_YB2 + ((size_t)l16 * 272 + dbase + reg) * 4);
        }
      }
      f32x4 acc1 = (f32x4){0.f, 0.f, 0.f, 0.f};
      cheb_mm_pre<1>(a9, sm + B_UT2, l16, quad, &acc1);
      if (dbase < NN) {
        short4v p;
#pragma unroll
        for (int reg = 0; reg < 4; ++reg) {
          float v = yr0[reg] - yr2[reg] + acc1[reg] + bb;
          p[reg] = f2bf(fmaxf(v, 0.f));
        }
        *(short4v*)(sm + B_H2T + ((size_t)l16 * SP + dbase) * 2) = p;
      }
    };
    body(w, aL0); body(w + 8, aL1); if (w == 0) body(16, aL2);
  }
  __syncthreads();

  // P6-L1: Z1[f][col] MFMA (A = H2T rows f, 1 m-tile; B = Wc1bT, K=288)
  for (int id = w; id < 7; id += NW) {
    f32x4 a1 = (f32x4){0.f, 0.f, 0.f, 0.f};
#pragma unroll
    for (int k = 0; k < 9; ++k) {
      short8 af = *(const short8*)(sm + B_H2T +
          ((size_t)l16 * SP + k * 32 + quad * 8) * 2);
      short8 bf = *(const short8*)(Wc1bT + (size_t)(id * 16 + l16) * KP + k * 32 + quad * 8);
      a1 = __builtin_amdgcn_mfma_f32_16x16x32_bf16(af, bf, a1, 0, 0, 0);
    }
    int col = id * 16 + l16;
    if (col < 100) {
      float bb = bc1[col];
#pragma unroll
      for (int reg = 0; reg < 4; ++reg)
        *(float*)(sm + B_Z1 + ((size_t)(quad * 4 + reg) * 116 + col) * 4) =
            fmaxf(a1[reg] + bb, 0.f);
    }
  }
  for (int i = t; i < 100 * 64; i += NTHR) { // stage W2s [100][64]
    int rr = i >> 6, c = i & 63;
    *(float*)(sm + B_W2S + ((size_t)rr * 64 + c) * 4) =
        (c < 60) ? Wc2[(size_t)rr * 60 + c] : 0.f;
  }
  if (t < 64) *(float*)(sm + B_W3S + (size_t)t * 4) = (t < 60) ? Wc3[t] : 0.f;
  __syncthreads();
  if (t < 64) {                              // L2: 16 rows x 64 cols
    int r2 = (t >> 3) * 2;
    int c8 = (t & 7) * 8;
    float a2[2][8];
#pragma unroll
    for (int i = 0; i < 2; ++i)
#pragma unroll
      for (int j = 0; j < 8; ++j) a2[i][j] = 0.f;
    const float* Z1p = (const float*)(sm + B_Z1);
    const float* W2p = (const float*)(sm + B_W2S);
#pragma unroll 4
    for (int k = 0; k < 100; ++k) {
      float x0 = Z1p[(size_t)r2 * 116 + k], x1 = Z1p[(size_t)(r2 + 1) * 116 + k];
      float4 wA = *(const float4*)(W2p + (size_t)k * 64 + c8);
      float4 wB = *(const float4*)(W2p + (size_t)k * 64 + c8 + 4);
      float wv[8] = {wA.x, wA.y, wA.z, wA.w, wB.x, wB.y, wB.z, wB.w};
#pragma unroll
      for (int j = 0; j < 8; ++j) { a2[0][j] += x0 * wv[j]; a2[1][j] += x1 * wv[j]; }
    }
    float* Z2p = (float*)(sm + B_Z2);
#pragma unroll
    for (int j = 0; j < 8; ++j) {
      int c = c8 + j;
      float bb = (c < 60) ? bc2[c] : 0.f;
      Z2p[(size_t)r2 * 64 + c] = fmaxf(a2[0][j] + bb, 0.f);
      Z2p[(size_t)(r2 + 1) * 64 + c] = fmaxf(a2[1][j] + bb, 0.f);
    }
  }
  __syncthreads();
  if (t < 16) {                              // L3: out = Z2 . Wc3 + bc3
    const float* Z2p = (const float*)(sm + B_Z2);
    const float* w3p = (const float*)(sm + B_W3S);
    float acc3 = bc3[0];
#pragma unroll
    for (int k = 0; k < 60; ++k) acc3 += Z2p[(size_t)t * 64 + k] * w3p[k];
    out[(size_t)g * 32 + h * 16 + t] = acc3;
  }
}

extern "C" void kernel_launch(void* const* d_in, const int* in_sizes, int n_in,
                              void* d_out, int out_size, void* d_ws, size_t ws_size,
                              hipStream_t stream) {
  (void)in_sizes; (void)n_in; (void)out_size; (void)ws_size;
  const float* x1  = (const float*)d_in[0];
  const int*   ei1 = (const int*)d_in[1];
  const float* ea1 = (const float*)d_in[2];
  const float* x2  = (const float*)d_in[3];
  const int*   ei2 = (const int*)d_in[4];
  const float* ea2 = (const float*)d_in[5];
  const float* W1  = (const float*)d_in[6];
  const float* b1  = (const float*)d_in[7];
  const float* W4  = (const float*)d_in[8];
  const float* b4  = (const float*)d_in[9];
  const float* Wc1 = (const float*)d_in[10];
  const float* bc1 = (const float*)d_in[11];
  const float* Wc2 = (const float*)d_in[12];
  const float* bc2 = (const float*)d_in[13];
  const float* Wc3 = (const float*)d_in[14];
  const float* bc3 = (const float*)d_in[15];

  char* ws = (char*)d_ws;
  float* dinv  = (float*)(ws + OFF_DINV);
  short* arena = (short*)(ws + OFF_ARENA);
  short* WbT   = (short*)(ws + OFF_WBT);
  short* Wc1bT = (short*)(ws + OFF_WC1BT);
  short* W4bT  = (short*)(ws + OFF_W4BT);
  short* Lb    = (short*)(ws + OFF_LB);
  float* Y     = (float*)(ws + OFF_Y);
  short* H1G   = (short*)(ws + OFF_H1G);
  float* out   = (float*)d_out;

  // L1: deg -> dinv (1024 thr, 8 edge iters) + WbT conversion
  k_prep<<<182, 1024, 0, stream>>>(ei1, ea1, ei2, ea2, W1, WbT, dinv);
  // L2: Laplacian build (full scan) || gemm1 (prefetched) || Wc1bT/W4bT tail
  k_build_gemm1<<<1814, 256, 0, stream>>>(ei1, ea1, ei2, ea2, dinv, Lb,
                                          x1, x2, WbT, Wc1, W4, Y, arena,
                                          Wc1bT, W4bT);
  // L3: megaA — P0-P2, feature-halved, 256 blocks (full machine)
  k_megaA<<<256, NTHR, 0, stream>>>(Lb, arena, Y, b1, H1G);
  // L4: megaB — P3-P6+cls, feature-16-split, 256 blocks (full machine)
  k_megaB<<<256, NTHR, 0, stream>>>(Lb, H1G, W4bT, Wc1bT,
                                    b4, bc1, Wc2, bc2, Wc3, bc3, out);
}

// Round 11
// 168.455 us; speedup vs baseline: 1.2380x; 1.0823x over previous
//
#include <hip/hip_runtime.h>
#include <hip/hip_bf16.h>

#define NN 268
#define NE 8192
#define KP 288   // padded node dim (268 -> 288)

typedef short short8 __attribute__((ext_vector_type(8)));   // 8 bf16 = 4 VGPR
typedef short short4v __attribute__((ext_vector_type(4)));  // 4 bf16 = 8B
typedef float f32x4 __attribute__((ext_vector_type(4)));

__device__ __forceinline__ short f2bf(float f) {
  __hip_bfloat16 h = __float2bfloat16(f);
  return *reinterpret_cast<short*>(&h);
}

// ---------------------------------------------------------------------------
// Workspace (bytes). Peak 55,835,648.  (layout identical to R10)
//   OFF_DINV  dinv  f32 [128][272]           139,264
//   OFF_ARENA Y2t   bf16[128][64][288]     4,718,592  (gemm1 out, megaA in)
//   OFF_WBT   WbT   bf16[192][288]           110,592  (prep out, gemm1 in)
//   OFF_WC1BT Wc1bT bf16[112][288]            64,512
//   OFF_W4BT  W4bT  bf16[96][64]              12,288
//   OFF_LB    Lb    bf16[128][272][288]   20,054,016
//   OFF_Y     Y     f32 [128][268][192]   26,345,472
//   OFF_H1G   H1G   bf16[128][268][64]     4,390,912  (megaA out, megaB in)
// Round-11: ONE change — int4/float4-vectorized edge scans (build family:
// 3 vector loads per 4 edges instead of 12 scalar; prep degree scan same).
// Counters r10: build_gemm1 = 50 us, ~25M scalar scan loads ~= 41 us of
// VMEM issue — the scan is instruction-issue bound, not bandwidth bound.
// Visit order shifts but int fixed-point accumulation is order-independent
// -> Lb bit-identical, absmax anchored at 0.0006103516.
// ---------------------------------------------------------------------------
#define OFF_DINV  0
#define OFF_ARENA 139264
#define ARENA_SLAB_S 18432   // shorts per graph: Y2t [64][288]
#define OFF_WBT   4857856
#define OFF_WC1BT 4968448
#define OFF_W4BT  5032960
#define OFF_LB    5045248
#define OFF_Y     25099264
#define OFF_H1G   51444736

// ---------------------------------------------------------------------------
// K1: prep, 182 blocks x 1024 threads.
//  [0,128):   per-graph degree -> dinv (vectorized: 2 iters x 3 vec loads).
//  [128,182): WbT conversion (54*1024 = 55296 elements exactly).
// ---------------------------------------------------------------------------
__global__ __launch_bounds__(1024) void k_prep(
    const int* __restrict__ ei1, const float* __restrict__ ea1,
    const int* __restrict__ ei2, const float* __restrict__ ea2,
    const float* __restrict__ W1, short* __restrict__ WbT,
    float* __restrict__ dinv) {
  int t = threadIdx.x;
  int b = blockIdx.x;
  if (b < 128) {
    int g = b;
    const int* ei = (g < 64) ? (ei1 + (size_t)g * 2 * NE) : (ei2 + (size_t)(g - 64) * 2 * NE);
    const float* ea = (g < 64) ? (ea1 + (size_t)g * NE) : (ea2 + (size_t)(g - 64) * NE);
    __shared__ unsigned degL[NN];
    if (t < NN) degL[t] = 0u;
    __syncthreads();
#pragma unroll
    for (int i = 0; i < 2; ++i) {
      int e = (i * 1024 + t) * 4;
      int4 s4 = *(const int4*)(ei + e);
      float4 w4 = *(const float4*)(ea + e);
      int4 d4 = *(const int4*)(ei + NE + e);
      int ss[4] = {s4.x, s4.y, s4.z, s4.w};
      int dd[4] = {d4.x, d4.y, d4.z, d4.w};
      float ww[4] = {w4.x, w4.y, w4.z, w4.w};
#pragma unroll
      for (int j = 0; j < 4; ++j) {
        if (ss[j] != dd[j])
          atomicAdd(&degL[ss[j]], (unsigned)lrintf(ww[j] * 1048576.f));
      }
    }
    __syncthreads();
    if (t < 272) {
      float r = 0.f;
      if (t < NN) {
        unsigned v = degL[t];
        if (v) r = rsqrtf((float)v * (1.f / 1048576.f));
      }
      dinv[(size_t)g * 272 + t] = r;
    }
  } else {
    int idx = (b - 128) * 1024 + t;  // 0..55295 = 192*288
    int n = idx / KP, kp = idx - n * KP;
    int kb = n >> 6, j = n & 63;
    float v = (kp < 268) ? W1[((size_t)kb * 268 + kp) * 64 + j] : 0.f;
    WbT[idx] = f2bf(v);
  }
}

// ---------------------------------------------------------------------------
// K2: fused Laplacian build + gemm1 + Wc1bT/W4bT tail. 1814 blocks.
//  [0,640):     gemm1 (MFMA), WbT B, A/B register prefetch (R10 verbatim).
//  [640,1664):  Laplacian 34-row tiles, VECTORIZED full edge scan.
//  [1664,1814): Wc1bT / W4bT conversion (megaB inputs).
// ---------------------------------------------------------------------------
__global__ __launch_bounds__(256) void k_build_gemm1(
    const int* __restrict__ ei1, const float* __restrict__ ea1,
    const int* __restrict__ ei2, const float* __restrict__ ea2,
    const float* __restrict__ dinv_all, short* __restrict__ Lb,
    const float* __restrict__ x1, const float* __restrict__ x2,
    const short* __restrict__ WbT, const float* __restrict__ Wc1,
    const float* __restrict__ W4, float* __restrict__ Y,
    short* __restrict__ Y2t, short* __restrict__ Wc1bT,
    short* __restrict__ W4bT) {
  __shared__ __align__(16) char smem[34 * 288 * 4 + 272 * 4];  // 40,256 B
  int t = threadIdx.x;
  int bx = blockIdx.x;
  if (bx < 640) {
    // ===================== gemm1 (MFMA, A/B prefetched) ====================
    int xcd = bx & 7, rest = bx >> 3;       // rest 0..79
    int g = xcd + 8 * (rest / 5);           // graph on XCD g&7
    int m0 = (rest % 5) * 64;
    const float* A32 = (g < 64) ? (x1 + (size_t)g * NN * 268)
                                : (x2 + (size_t)(g - 64) * NN * 268);
    float* Yg = Y + (size_t)g * NN * 192;
    short* Y2tg = Y2t + (size_t)g * ARENA_SLAB_S;
    short (*As)[40] = (short(*)[40])smem;                     //  5,120 B
    short (*Bs)[40] = (short(*)[40])(smem + 5120);            // 15,360 B
    int w = t >> 6, lane = t & 63;
    int quad = lane >> 4, l16 = lane & 15;
    int mh = w & 1, nh = w >> 1;
    f32x4 acc[2][6];
#pragma unroll
    for (int mi = 0; mi < 2; ++mi)
#pragma unroll
      for (int ni = 0; ni < 6; ++ni) acc[mi][ni] = (f32x4){0.f, 0.f, 0.f, 0.f};

    int sr = t >> 2, sko = (t & 3) * 8;
    float4 pva, pvb;
    short8 pB[3];
    auto loadA = [&](int K0) {
      int row = m0 + sr, k = K0 + sko;
      pva = make_float4(0.f, 0.f, 0.f, 0.f); pvb = pva;
      if (row < NN && k < 268) pva = *(const float4*)(A32 + (size_t)row * 268 + k);
      if (row < NN && k + 4 < 268) pvb = *(const float4*)(A32 + (size_t)row * 268 + k + 4);
    };
    auto loadB = [&](int K0) {
#pragma unroll
      for (int i = 0; i < 3; ++i)
        pB[i] = *(const short8*)(WbT + (size_t)(sr + i * 64) * KP + K0 + sko);
    };
    loadA(0); loadB(0);
    for (int k0 = 0; k0 < KP; k0 += 32) {
      {
        short8 s;
        const float* fa = (const float*)&pva;
        const float* fb = (const float*)&pvb;
#pragma unroll
        for (int j = 0; j < 4; ++j) { s[j] = f2bf(fa[j]); s[4 + j] = f2bf(fb[j]); }
        *(short8*)(&As[sr][sko]) = s;
      }
#pragma unroll
      for (int i = 0; i < 3; ++i)
        *(short8*)(&Bs[sr + i * 64][sko]) = pB[i];
      __syncthreads();
      if (k0 + 32 < KP) { loadA(k0 + 32); loadB(k0 + 32); }  // hides under MFMA
      short8 af[2], bfr[6];
#pragma unroll
      for (int mi = 0; mi < 2; ++mi)
        af[mi] = *(const short8*)(&As[(mh * 2 + mi) * 16 + l16][quad * 8]);
#pragma unroll
      for (int ni = 0; ni < 6; ++ni)
        bfr[ni] = *(const short8*)(&Bs[(nh * 6 + ni) * 16 + l16][quad * 8]);
#pragma unroll
      for (int mi = 0; mi < 2; ++mi)
#pragma unroll
        for (int ni = 0; ni < 6; ++ni)
          acc[mi][ni] = __builtin_amdgcn_mfma_f32_16x16x32_bf16(af[mi], bfr[ni], acc[mi][ni], 0, 0, 0);
      __syncthreads();
    }
    // C/D: col = lane&15, row = quad*4 + reg
#pragma unroll
    for (int mi = 0; mi < 2; ++mi) {
      int rbase = m0 + (mh * 2 + mi) * 16 + quad * 4;
#pragma unroll
      for (int reg = 0; reg < 4; ++reg) {
        int row = rbase + reg;
        if (row < NN) {
#pragma unroll
          for (int ni = 0; ni < 6; ++ni) {
            int col = (nh * 6 + ni) * 16 + l16;
            Yg[(size_t)row * 192 + col] = acc[mi][ni][reg];
          }
        }
      }
      if (rbase < NN) {  // rbase % 4 == 0, never straddles 268
#pragma unroll
        for (int ni = 0; ni < 6; ++ni) {
          int col = (nh * 6 + ni) * 16 + l16;
          if (col >= 128) {
            short4v p;
#pragma unroll
            for (int reg = 0; reg < 4; ++reg) p[reg] = f2bf(acc[mi][ni][reg]);
            *(short4v*)(Y2tg + (size_t)(col - 128) * KP + rbase) = p;
          }
        }
      }
    }
  } else if (bx < 1664) {
    // ============ Laplacian build (vectorized full scan) ===================
    int l = bx - 640;                // 0..1023 = 8 xcd * 16 g * 8 tiles
    int xcd = l & 7, rest = l >> 3;  // rest 0..127
    int g = xcd + 8 * (rest & 15);
    int tile = rest >> 4;            // 0..7
    int r0 = tile * 34;
    const int* ei = (g < 64) ? (ei1 + (size_t)g * 2 * NE) : (ei2 + (size_t)(g - 64) * 2 * NE);
    const float* ea = (g < 64) ? (ea1 + (size_t)g * NE) : (ea2 + (size_t)(g - 64) * NE);
    int* LrowI = (int*)smem;                      // 34*288 ints = 39,168 B
    float* dv = (float*)(smem + 39168);           // 272 floats
    for (int i = t; i < 34 * 288; i += 256) LrowI[i] = 0;
    for (int i = t; i < 272; i += 256) dv[i] = dinv_all[(size_t)g * 272 + i];
    __syncthreads();
#pragma unroll
    for (int i = 0; i < 8; ++i) {
      int e = (i * 256 + t) * 4;
      int4 d4 = *(const int4*)(ei + NE + e);
      int4 s4 = *(const int4*)(ei + e);
      float4 w4 = *(const float4*)(ea + e);
      int ss[4] = {s4.x, s4.y, s4.z, s4.w};
      int dd[4] = {d4.x, d4.y, d4.z, d4.w};
      float ww[4] = {w4.x, w4.y, w4.z, w4.w};
#pragma unroll
      for (int j = 0; j < 4; ++j) {
        int d = dd[j], s = ss[j];
        if (d >= r0 && d < r0 + 34 && s != d) {
          atomicAdd(&LrowI[(d - r0) * 288 + s],
                    (int)lrintf(-dv[s] * ww[j] * dv[d] * 16777216.f));  // ds_add
        }
      }
    }
    __syncthreads();
    short* Lbg = Lb + (size_t)g * 272 * KP + (size_t)r0 * KP;
    for (int i = t; i < 34 * 288; i += 256)
      Lbg[i] = f2bf((float)LrowI[i] * (1.f / 16777216.f));
  } else {
    // ===================== Wc1bT / W4bT tail (megaB inputs) ================
    int idx = (bx - 1664) * 256 + t;  // 0..38399
    if (idx < 112 * KP) {
      int n = idx / KP, k = idx - n * KP;
      float v = (n < 100 && k < 268) ? Wc1[(size_t)k * 100 + n] : 0.f;
      Wc1bT[idx] = f2bf(v);
    } else {
      int i4 = idx - 112 * KP;       // 0..6143
      int n = i4 >> 6, k = i4 & 63;  // n in [0,96), k in [0,64)
      W4bT[i4] = f2bf(W4[(((size_t)(n >> 5)) * 64 + k) * 32 + (n & 31)]);
    }
  }
}

// ---------------------------------------------------------------------------
// Shared mega helpers (R8-verified): L fragment hoist + LDS-B MFMA body.
// ---------------------------------------------------------------------------
#define SP 296
#define NW 8
#define NTHR 512

__device__ __forceinline__ void load_a9(const short* __restrict__ Lbg,
                                        int mt, int l16, int quad, short8* a9) {
  const short* Arow = Lbg + (size_t)(mt * 16 + l16) * KP + quad * 8;
#pragma unroll
  for (int k = 0; k < 9; ++k) a9[k] = *(const short8*)(Arow + k * 32);
}

template <int NTN>
__device__ __forceinline__ void cheb_mm_pre(const short8* a9,
                                            const char* B0, int l16, int quad,
                                            f32x4* acc) {
#pragma unroll
  for (int k = 0; k < 9; ++k) {
#pragma unroll
    for (int nt = 0; nt < NTN; ++nt) {
      short8 bf = *(const short8*)(B0 +
          ((size_t)(nt * 16 + l16) * SP + k * 32 + quad * 8) * 2);
      acc[nt] = __builtin_amdgcn_mfma_f32_16x16x32_bf16(a9[k], bf, acc[nt], 0, 0, 0);
    }
  }
}

// ---------------------------------------------------------------------------
// K3: megaA (R9 verbatim) — P0/P1/P2 by feature half. 256 blocks, 512 thr.
// ---------------------------------------------------------------------------
#define A_Y2H 0
#define A_UTH 18944
__global__ __launch_bounds__(NTHR, 1) void k_megaA(
    const short* __restrict__ Lb, const short* __restrict__ arena,
    const float* __restrict__ Y, const float* __restrict__ b1,
    short* __restrict__ H1G) {
  __shared__ __align__(16) char sm[37888];
  int b = blockIdx.x;
  int xcd = b & 7, idx = b >> 3;
  int g = xcd + 8 * (idx & 15);
  int h = idx >> 4;                    // feature half 0/1
  int t = threadIdx.x;
  int w = t >> 6, lane = t & 63;
  int quad = lane >> 4, l16 = lane & 15;
  const short* Lbg = Lb + (size_t)g * 272 * KP;
  const short* Y2tg = arena + (size_t)g * ARENA_SLAB_S + (size_t)h * 32 * KP;
  const float* Yg = Y + (size_t)g * NN * 192;
  short* H1gg = H1G + (size_t)g * 268 * 64;

  short8 aL0[9], aL1[9], aL2[9];
  load_a9(Lbg, w, l16, quad, aL0);
  load_a9(Lbg, w + 8, l16, quad, aL1);
  if (w == 0) load_a9(Lbg, 16, l16, quad, aL2);

  // P0: stage own 32 Y2t rows; cols >=268 zeroed (poison-safe)
  for (int i = t; i < 32 * 37; i += NTHR) {
    int r = i / 37, c = (i - r * 37) * 8;
    short8 v = {0, 0, 0, 0, 0, 0, 0, 0};
    if (c < 264) {
      v = *(const short8*)(Y2tg + (size_t)r * KP + c);
    } else if (c == 264) {
      v = *(const short8*)(Y2tg + (size_t)r * KP + 264);
      v[4] = 0; v[5] = 0; v[6] = 0; v[7] = 0;
    }
    *(short8*)(sm + A_Y2H + ((size_t)r * SP + c) * 2) = v;
  }
  for (int i = t; i < 32 * 20; i += NTHR) {  // zero Ut K-pad cols 268..288
    int f = i / 20, d = 268 + (i - f * 20);
    *(short*)(sm + A_UTH + ((size_t)f * SP + d) * 2) = 0;
  }
  __syncthreads();

  // P1: Ut[f_loc][d] = bf16(Y1[d][f_glob] + 2*(L@Y2)[d][f_glob])
  {
    auto body = [&](int mt, const short8* a9) {
      int dbase = mt * 16 + quad * 4;
      float yr[2][4];
      if (dbase < NN) {
#pragma unroll
        for (int nt = 0; nt < 2; ++nt)
#pragma unroll
          for (int reg = 0; reg < 4; ++reg)
            yr[nt][reg] = Yg[(size_t)(dbase + reg) * 192 + 64 + h * 32 + nt * 16 + l16];
      }
      f32x4 acc[2];
#pragma unroll
      for (int nt = 0; nt < 2; ++nt) acc[nt] = (f32x4){0.f, 0.f, 0.f, 0.f};
      cheb_mm_pre<2>(a9, sm + A_Y2H, l16, quad, acc);
      if (dbase < NN) {
#pragma unroll
        for (int nt = 0; nt < 2; ++nt) {
          int f_loc = nt * 16 + l16;
          short4v p;
#pragma unroll
          for (int reg = 0; reg < 4; ++reg)
            p[reg] = f2bf(yr[nt][reg] + 2.f * acc[nt][reg]);
          *(short4v*)(sm + A_UTH + ((size_t)f_loc * SP + dbase) * 2) = p;
        }
      }
    };
    body(w, aL0); body(w + 8, aL1); if (w == 0) body(16, aL2);
  }
  __syncthreads();

  // P2: H1[d][f_glob] = relu(Y0 - Y2 + (L@Ut) + b1) -> H1G global
  {
    auto body = [&](int mt, const short8* a9) {
      int dbase = mt * 16 + quad * 4;
      float yr0[2][4], yr2[2][4];
      if (dbase < NN) {
#pragma unroll
        for (int nt = 0; nt < 2; ++nt)
#pragma unroll
          for (int reg = 0; reg < 4; ++reg) {
            int fg = h * 32 + nt * 16 + l16;
            yr0[nt][reg] = Yg[(size_t)(dbase + reg) * 192 + fg];
            yr2[nt][reg] = Yg[(size_t)(dbase + reg) * 192 + 128 + fg];
          }
      }
      f32x4 acc[2];
#pragma unroll
      for (int nt = 0; nt < 2; ++nt) acc[nt] = (f32x4){0.f, 0.f, 0.f, 0.f};
      cheb_mm_pre<2>(a9, sm + A_UTH, l16, quad, acc);
      if (dbase < NN) {
#pragma unroll
        for (int nt = 0; nt < 2; ++nt) {
          int fg = h * 32 + nt * 16 + l16;
          float bb = b1[fg];
#pragma unroll
          for (int reg = 0; reg < 4; ++reg) {
            int d = dbase + reg;
            float v = yr0[nt][reg] - yr2[nt][reg] + acc[nt][reg] + bb;
            H1gg[(size_t)d * 64 + fg] = f2bf(fmaxf(v, 0.f));
          }
        }
      }
    };
    body(w, aL0); body(w + 8, aL1); if (w == 0) body(16, aL2);
  }
}

// ---------------------------------------------------------------------------
// K4: megaB (R9 verbatim) — P3..P6+cls by output-feature 16-group.
// 256 blocks, 512 thr.
// ---------------------------------------------------------------------------
#define B_H1S 0
#define B_W4S 39168
#define B_YB0 52992
#define B_YB1 70400
#define B_YB2 87808
#define B_YBB 105216
#define B_UT2 0
#define B_H2T 9472
#define B_Z1  18944
#define B_W2S 26368
#define B_Z2  52992      // overlays YB0; used only in P6 (after YB0 dead)
#define B_W3S 57088
__global__ __launch_bounds__(NTHR, 1) void k_megaB(
    const short* __restrict__ Lb, const short* __restrict__ H1G,
    const short* __restrict__ W4bT, const short* __restrict__ Wc1bT,
    const float* __restrict__ b4, const float* __restrict__ bc1,
    const float* __restrict__ Wc2, const float* __restrict__ bc2,
    const float* __restrict__ Wc3, const float* __restrict__ bc3,
    float* __restrict__ out) {
  __shared__ __align__(16) char sm[114688];
  int b = blockIdx.x;
  int xcd = b & 7, idx = b >> 3;
  int g = xcd + 8 * (idx & 15);
  int h = idx >> 4;                    // output-feature 16-group 0/1
  int t = threadIdx.x;
  int w = t >> 6, lane = t & 63;
  int quad = lane >> 4, l16 = lane & 15;
  const short* Lbg = Lb + (size_t)g * 272 * KP;
  const short* H1gg = H1G + (size_t)g * 268 * 64;

  short8 aL0[9], aL1[9], aL2[9];
  load_a9(Lbg, w, l16, quad, aL0);
  load_a9(Lbg, w + 8, l16, quad, aL1);
  if (w == 0) load_a9(Lbg, 16, l16, quad, aL2);

  // stage H1s [272][72] from H1G (rows >=268 zero; col group 8 = pad zeros)
  for (int i = t; i < 272 * 9; i += NTHR) {
    int r = i / 9, cg = i - r * 9;
    short8 v = {0, 0, 0, 0, 0, 0, 0, 0};
    if (cg < 8 && r < 268) v = *(const short8*)(H1gg + (size_t)r * 64 + cg * 8);
    *(short8*)(sm + B_H1S + ((size_t)r * 72 + cg * 8) * 2) = v;
  }
  for (int i = t; i < 96 * 8; i += NTHR) {   // W4s [96][72]
    int r = i >> 3, ko = (i & 7) * 8;
    *(short8*)(sm + B_W4S + ((size_t)r * 72 + ko) * 2) =
        *(const short8*)(W4bT + r * 64 + ko);
  }
  for (int i = t; i < 16 * 20; i += NTHR) {  // zero YbB K-pad cols 268..288
    int f = i / 20, d = 268 + (i - f * 20);
    *(short*)(sm + B_YBB + ((size_t)f * SP + d) * 2) = 0;
  }
  __syncthreads();

  // P3: 3 own c-tiles x 17 d-tiles, K=64 over f
  for (int id = w; id < 51; id += NW) {
    int ci = id / 17, nt = id - ci * 17;     // ci 0..2 -> c-tile h + 2*ci
    int ct = h + 2 * ci;
    f32x4 a1 = (f32x4){0.f, 0.f, 0.f, 0.f};
#pragma unroll
    for (int kc = 0; kc < 2; ++kc) {
      short8 af = *(const short8*)(sm + B_W4S +
          ((size_t)(ct * 16 + l16) * 72 + kc * 32 + quad * 8) * 2);
      short8 bf = *(const short8*)(sm + B_H1S +
          ((size_t)(nt * 16 + l16) * 72 + kc * 32 + quad * 8) * 2);
      a1 = __builtin_amdgcn_mfma_f32_16x16x32_bf16(af, bf, a1, 0, 0, 0);
    }
    int d = nt * 16 + l16;
    if (d < NN) {
#pragma unroll
      for (int reg = 0; reg < 4; ++reg) {
        int fl = quad * 4 + reg;             // local row in the 16-tile
        float a = a1[reg];
        if (ci == 0) {
          *(float*)(sm + B_YB0 + ((size_t)fl * 272 + d) * 4) = a;
        } else if (ci == 1) {
          *(float*)(sm + B_YB1 + ((size_t)fl * 272 + d) * 4) = a;
        } else {
          *(float*)(sm + B_YB2 + ((size_t)fl * 272 + d) * 4) = a;
          *(short*)(sm + B_YBB + ((size_t)fl * SP + d) * 2) = f2bf(a);
        }
      }
    }
  }
  __syncthreads();

  // zero Ut2/H2T K-pad cols (regions overlay dead H1s; safe after barrier)
  for (int i = t; i < 16 * 20; i += NTHR) {
    int f = i / 20, d = 268 + (i - f * 20);
    *(short*)(sm + B_UT2 + ((size_t)f * SP + d) * 2) = 0;
    *(short*)(sm + B_H2T + ((size_t)f * SP + d) * 2) = 0;
  }

  // P4: Ut2[f][d] = bf16(Yb1[d][f] + 2*(L@Yb2)[d][f])
  {
    auto body = [&](int mt, const short8* a9) {
      int dbase = mt * 16 + quad * 4;
      float yr[4];
      if (dbase < NN) {
#pragma unroll
        for (int reg = 0; reg < 4; ++reg)
          yr[reg] = *(const float*)(sm + B_YB1 + ((size_t)l16 * 272 + dbase + reg) * 4);
      }
      f32x4 acc1 = (f32x4){0.f, 0.f, 0.f, 0.f};
      cheb_mm_pre<1>(a9, sm + B_YBB, l16, quad, &acc1);
      if (dbase < NN) {
        short4v p;
#pragma unroll
        for (int reg = 0; reg < 4; ++reg)
          p[reg] = f2bf(yr[reg] + 2.f * acc1[reg]);
        *(short4v*)(sm + B_UT2 + ((size_t)l16 * SP + dbase) * 2) = p;
      }
    };
    body(w, aL0); body(w + 8, aL1); if (w == 0) body(16, aL2);
  }
  __syncthreads();

  // P5: H2T[f][d] = relu(Yb0 - Yb2 + (L@Ut2) + b4[f_glob])
  {
    float bb = b4[h * 16 + l16];
    auto body = [&](int mt, const short8* a9) {
      int dbase = mt * 16 + quad * 4;
      float yr0[4], yr2[4];
      if (dbase < NN) {
#pragma unroll
        for (int reg = 0; reg < 4; ++reg) {
          yr0[reg] = *(const float*)(sm + B_YB0 + ((size_t)l16 * 272 + dbase + reg) * 4);
          yr2[reg] = *(const float*)(sm + B_YB2 + ((size_t)l16 * 272 + dbase + reg) * 4);
        }
      }
      f32x4 acc1 = (f32x4){0.f, 0.f, 0.f, 0.f};
      cheb_mm_pre<1>(a9, sm + B_UT2, l16, quad, &acc1);
      if (dbase < NN) {
        short4v p;
#pragma unroll
        for (int reg = 0; reg < 4; ++reg) {
          float v = yr0[reg] - yr2[reg] + acc1[reg] + bb;
          p[reg] = f2bf(fmaxf(v, 0.f));
        }
        *(short4v*)(sm + B_H2T + ((size_t)l16 * SP + dbase) * 2) = p;
      }
    };
    body(w, aL0); body(w + 8, aL1); if (w == 0) body(16, aL2);
  }
  __syncthreads();

  // P6-L1: Z1[f][col] MFMA (A = H2T rows f, 1 m-tile; B = Wc1bT, K=288)
  for (int id = w; id < 7; id += NW) {
    f32x4 a1 = (f32x4){0.f, 0.f, 0.f, 0.f};
#pragma unroll
    for (int k = 0; k < 9; ++k) {
      short8 af = *(const short8*)(sm + B_H2T +
          ((size_t)l16 * SP + k * 32 + quad * 8) * 2);
      short8 bf = *(const short8*)(Wc1bT + (size_t)(id * 16 + l16) * KP + k * 32 + quad * 8);
      a1 = __builtin_amdgcn_mfma_f32_16x16x32_bf16(af, bf, a1, 0, 0, 0);
    }
    int col = id * 16 + l16;
    if (col < 100) {
      float bb = bc1[col];
#pragma unroll
      for (int reg = 0; reg < 4; ++reg)
        *(float*)(sm + B_Z1 + ((size_t)(quad * 4 + reg) * 116 + col) * 4) =
            fmaxf(a1[reg] + bb, 0.f);
    }
  }
  for (int i = t; i < 100 * 64; i += NTHR) { // stage W2s [100][64]
    int rr = i >> 6, c = i & 63;
    *(float*)(sm + B_W2S + ((size_t)rr * 64 + c) * 4) =
        (c < 60) ? Wc2[(size_t)rr * 60 + c] : 0.f;
  }
  if (t < 64) *(float*)(sm + B_W3S + (size_t)t * 4) = (t < 60) ? Wc3[t] : 0.f;
  __syncthreads();
  if (t < 64) {                              // L2: 16 rows x 64 cols
    int r2 = (t >> 3) * 2;
    int c8 = (t & 7) * 8;
    float a2[2][8];
#pragma unroll
    for (int i = 0; i < 2; ++i)
#pragma unroll
      for (int j = 0; j < 8; ++j) a2[i][j] = 0.f;
    const float* Z1p = (const float*)(sm + B_Z1);
    const float* W2p = (const float*)(sm + B_W2S);
#pragma unroll 4
    for (int k = 0; k < 100; ++k) {
      float x0 = Z1p[(size_t)r2 * 116 + k], x1 = Z1p[(size_t)(r2 + 1) * 116 + k];
      float4 wA = *(const float4*)(W2p + (size_t)k * 64 + c8);
      float4 wB = *(const float4*)(W2p + (size_t)k * 64 + c8 + 4);
      float wv[8] = {wA.x, wA.y, wA.z, wA.w, wB.x, wB.y, wB.z, wB.w};
#pragma unroll
      for (int j = 0; j < 8; ++j) { a2[0][j] += x0 * wv[j]; a2[1][j] += x1 * wv[j]; }
    }
    float* Z2p = (float*)(sm + B_Z2);
#pragma unroll
    for (int j = 0; j < 8; ++j) {
      int c = c8 + j;
      float bb = (c < 60) ? bc2[c] : 0.f;
      Z2p[(size_t)r2 * 64 + c] = fmaxf(a2[0][j] + bb, 0.f);
      Z2p[(size_t)(r2 + 1) * 64 + c] = fmaxf(a2[1][j] + bb, 0.f);
    }
  }
  __syncthreads();
  if (t < 16) {                              // L3: out = Z2 . Wc3 + bc3
    const float* Z2p = (const float*)(sm + B_Z2);
    const float* w3p = (const float*)(sm + B_W3S);
    float acc3 = bc3[0];
#pragma unroll
    for (int k = 0; k < 60; ++k) acc3 += Z2p[(size_t)t * 64 + k] * w3p[k];
    out[(size_t)g * 32 + h * 16 + t] = acc3;
  }
}

extern "C" void kernel_launch(void* const* d_in, const int* in_sizes, int n_in,
                              void* d_out, int out_size, void* d_ws, size_t ws_size,
                              hipStream_t stream) {
  (void)in_sizes; (void)n_in; (void)out_size; (void)ws_size;
  const float* x1  = (const float*)d_in[0];
  const int*   ei1 = (const int*)d_in[1];
  const float* ea1 = (const float*)d_in[2];
  const float* x2  = (const float*)d_in[3];
  const int*   ei2 = (const int*)d_in[4];
  const float* ea2 = (const float*)d_in[5];
  const float* W1  = (const float*)d_in[6];
  const float* b1  = (const float*)d_in[7];
  const float* W4  = (const float*)d_in[8];
  const float* b4  = (const float*)d_in[9];
  const float* Wc1 = (const float*)d_in[10];
  const float* bc1 = (const float*)d_in[11];
  const float* Wc2 = (const float*)d_in[12];
  const float* bc2 = (const float*)d_in[13];
  const float* Wc3 = (const float*)d_in[14];
  const float* bc3 = (const float*)d_in[15];

  char* ws = (char*)d_ws;
  float* dinv  = (float*)(ws + OFF_DINV);
  short* arena = (short*)(ws + OFF_ARENA);
  short* WbT   = (short*)(ws + OFF_WBT);
  short* Wc1bT = (short*)(ws + OFF_WC1BT);
  short* W4bT  = (short*)(ws + OFF_W4BT);
  short* Lb    = (short*)(ws + OFF_LB);
  float* Y     = (float*)(ws + OFF_Y);
  short* H1G   = (short*)(ws + OFF_H1G);
  float* out   = (float*)d_out;

  // L1: deg -> dinv (vectorized scan) + WbT conversion
  k_prep<<<182, 1024, 0, stream>>>(ei1, ea1, ei2, ea2, W1, WbT, dinv);
  // L2: Laplacian build (vectorized scan) || gemm1 (prefetched) || conv tail
  k_build_gemm1<<<1814, 256, 0, stream>>>(ei1, ea1, ei2, ea2, dinv, Lb,
                                          x1, x2, WbT, Wc1, W4, Y, arena,
                                          Wc1bT, W4bT);
  // L3: megaA — P0-P2, feature-halved, 256 blocks (full machine)
  k_megaA<<<256, NTHR, 0, stream>>>(Lb, arena, Y, b1, H1G);
  // L4: megaB — P3-P6+cls, feature-16-split, 256 blocks (full machine)
  k_megaB<<<256, NTHR, 0, stream>>>(Lb, H1G, W4bT, Wc1bT,
                                    b4, bc1, Wc2, bc2, Wc3, bc3, out);
}

// Round 12
// 163.513 us; speedup vs baseline: 1.2755x; 1.0302x over previous
//
#include <hip/hip_runtime.h>
#include <hip/hip_bf16.h>

#define NN 268
#define NE 8192
#define KP 288   // padded node dim (268 -> 288)

typedef short short8 __attribute__((ext_vector_type(8)));   // 8 bf16 = 4 VGPR
typedef short short4v __attribute__((ext_vector_type(4)));  // 4 bf16 = 8B
typedef float f32x4 __attribute__((ext_vector_type(4)));

__device__ __forceinline__ short f2bf(float f) {
  __hip_bfloat16 h = __float2bfloat16(f);
  return *reinterpret_cast<short*>(&h);
}

// ---------------------------------------------------------------------------
// Workspace (bytes). Peak 55,835,648.  (layout identical to R10/R11)
//   OFF_DINV  dinv  f32 [128][272]           139,264
//   OFF_ARENA Y2t   bf16[128][64][288]     4,718,592  (gemm1 out, megaA in)
//   OFF_WBT   WbT   bf16[192][288]           110,592  (prep out, gemm1 in)
//   OFF_WC1BT Wc1bT bf16[112][288]            64,512
//   OFF_W4BT  W4bT  bf16[96][64]              12,288
//   OFF_LB    Lb    bf16[128][272][288]   20,054,016
//   OFF_Y     Y     f32 [128][268][192]   26,345,472
//   OFF_H1G   H1G   bf16[128][268][64]     4,390,912  (megaA out, megaB in)
// Round-12: ONE change — vectorize the build family's LDS zero (int4) and
// Lb writeback (short8, 16B coalesced stores). R11 counters: all kernels now
// below the 41-us fill threshold; instruction audit shows the build family
// still issues ~78K wave-iters of scalar zero/writeback that vectorize 4-8x.
// Same values, same f2bf points, same int accumulation -> Lb bit-identical.
// ---------------------------------------------------------------------------
#define OFF_DINV  0
#define OFF_ARENA 139264
#define ARENA_SLAB_S 18432   // shorts per graph: Y2t [64][288]
#define OFF_WBT   4857856
#define OFF_WC1BT 4968448
#define OFF_W4BT  5032960
#define OFF_LB    5045248
#define OFF_Y     25099264
#define OFF_H1G   51444736

// ---------------------------------------------------------------------------
// K1: prep, 182 blocks x 1024 threads. (R11 verbatim)
//  [0,128):   per-graph degree -> dinv (vectorized: 2 iters x 3 vec loads).
//  [128,182): WbT conversion (54*1024 = 55296 elements exactly).
// ---------------------------------------------------------------------------
__global__ __launch_bounds__(1024) void k_prep(
    const int* __restrict__ ei1, const float* __restrict__ ea1,
    const int* __restrict__ ei2, const float* __restrict__ ea2,
    const float* __restrict__ W1, short* __restrict__ WbT,
    float* __restrict__ dinv) {
  int t = threadIdx.x;
  int b = blockIdx.x;
  if (b < 128) {
    int g = b;
    const int* ei = (g < 64) ? (ei1 + (size_t)g * 2 * NE) : (ei2 + (size_t)(g - 64) * 2 * NE);
    const float* ea = (g < 64) ? (ea1 + (size_t)g * NE) : (ea2 + (size_t)(g - 64) * NE);
    __shared__ unsigned degL[NN];
    if (t < NN) degL[t] = 0u;
    __syncthreads();
#pragma unroll
    for (int i = 0; i < 2; ++i) {
      int e = (i * 1024 + t) * 4;
      int4 s4 = *(const int4*)(ei + e);
      float4 w4 = *(const float4*)(ea + e);
      int4 d4 = *(const int4*)(ei + NE + e);
      int ss[4] = {s4.x, s4.y, s4.z, s4.w};
      int dd[4] = {d4.x, d4.y, d4.z, d4.w};
      float ww[4] = {w4.x, w4.y, w4.z, w4.w};
#pragma unroll
      for (int j = 0; j < 4; ++j) {
        if (ss[j] != dd[j])
          atomicAdd(&degL[ss[j]], (unsigned)lrintf(ww[j] * 1048576.f));
      }
    }
    __syncthreads();
    if (t < 272) {
      float r = 0.f;
      if (t < NN) {
        unsigned v = degL[t];
        if (v) r = rsqrtf((float)v * (1.f / 1048576.f));
      }
      dinv[(size_t)g * 272 + t] = r;
    }
  } else {
    int idx = (b - 128) * 1024 + t;  // 0..55295 = 192*288
    int n = idx / KP, kp = idx - n * KP;
    int kb = n >> 6, j = n & 63;
    float v = (kp < 268) ? W1[((size_t)kb * 268 + kp) * 64 + j] : 0.f;
    WbT[idx] = f2bf(v);
  }
}

// ---------------------------------------------------------------------------
// K2: fused Laplacian build + gemm1 + Wc1bT/W4bT tail. 1814 blocks.
//  [0,640):     gemm1 (MFMA), WbT B, A/B register prefetch (R10 verbatim).
//  [640,1664):  Laplacian 34-row tiles: vectorized scan (R11) + NEW
//               vectorized LDS zero (int4) + vectorized Lb writeback (short8).
//  [1664,1814): Wc1bT / W4bT conversion (megaB inputs).
// ---------------------------------------------------------------------------
__global__ __launch_bounds__(256) void k_build_gemm1(
    const int* __restrict__ ei1, const float* __restrict__ ea1,
    const int* __restrict__ ei2, const float* __restrict__ ea2,
    const float* __restrict__ dinv_all, short* __restrict__ Lb,
    const float* __restrict__ x1, const float* __restrict__ x2,
    const short* __restrict__ WbT, const float* __restrict__ Wc1,
    const float* __restrict__ W4, float* __restrict__ Y,
    short* __restrict__ Y2t, short* __restrict__ Wc1bT,
    short* __restrict__ W4bT) {
  __shared__ __align__(16) char smem[34 * 288 * 4 + 272 * 4];  // 40,256 B
  int t = threadIdx.x;
  int bx = blockIdx.x;
  if (bx < 640) {
    // ===================== gemm1 (MFMA, A/B prefetched) ====================
    int xcd = bx & 7, rest = bx >> 3;       // rest 0..79
    int g = xcd + 8 * (rest / 5);           // graph on XCD g&7
    int m0 = (rest % 5) * 64;
    const float* A32 = (g < 64) ? (x1 + (size_t)g * NN * 268)
                                : (x2 + (size_t)(g - 64) * NN * 268);
    float* Yg = Y + (size_t)g * NN * 192;
    short* Y2tg = Y2t + (size_t)g * ARENA_SLAB_S;
    short (*As)[40] = (short(*)[40])smem;                     //  5,120 B
    short (*Bs)[40] = (short(*)[40])(smem + 5120);            // 15,360 B
    int w = t >> 6, lane = t & 63;
    int quad = lane >> 4, l16 = lane & 15;
    int mh = w & 1, nh = w >> 1;
    f32x4 acc[2][6];
#pragma unroll
    for (int mi = 0; mi < 2; ++mi)
#pragma unroll
      for (int ni = 0; ni < 6; ++ni) acc[mi][ni] = (f32x4){0.f, 0.f, 0.f, 0.f};

    int sr = t >> 2, sko = (t & 3) * 8;
    float4 pva, pvb;
    short8 pB[3];
    auto loadA = [&](int K0) {
      int row = m0 + sr, k = K0 + sko;
      pva = make_float4(0.f, 0.f, 0.f, 0.f); pvb = pva;
      if (row < NN && k < 268) pva = *(const float4*)(A32 + (size_t)row * 268 + k);
      if (row < NN && k + 4 < 268) pvb = *(const float4*)(A32 + (size_t)row * 268 + k + 4);
    };
    auto loadB = [&](int K0) {
#pragma unroll
      for (int i = 0; i < 3; ++i)
        pB[i] = *(const short8*)(WbT + (size_t)(sr + i * 64) * KP + K0 + sko);
    };
    loadA(0); loadB(0);
    for (int k0 = 0; k0 < KP; k0 += 32) {
      {
        short8 s;
        const float* fa = (const float*)&pva;
        const float* fb = (const float*)&pvb;
#pragma unroll
        for (int j = 0; j < 4; ++j) { s[j] = f2bf(fa[j]); s[4 + j] = f2bf(fb[j]); }
        *(short8*)(&As[sr][sko]) = s;
      }
#pragma unroll
      for (int i = 0; i < 3; ++i)
        *(short8*)(&Bs[sr + i * 64][sko]) = pB[i];
      __syncthreads();
      if (k0 + 32 < KP) { loadA(k0 + 32); loadB(k0 + 32); }  // hides under MFMA
      short8 af[2], bfr[6];
#pragma unroll
      for (int mi = 0; mi < 2; ++mi)
        af[mi] = *(const short8*)(&As[(mh * 2 + mi) * 16 + l16][quad * 8]);
#pragma unroll
      for (int ni = 0; ni < 6; ++ni)
        bfr[ni] = *(const short8*)(&Bs[(nh * 6 + ni) * 16 + l16][quad * 8]);
#pragma unroll
      for (int mi = 0; mi < 2; ++mi)
#pragma unroll
        for (int ni = 0; ni < 6; ++ni)
          acc[mi][ni] = __builtin_amdgcn_mfma_f32_16x16x32_bf16(af[mi], bfr[ni], acc[mi][ni], 0, 0, 0);
      __syncthreads();
    }
    // C/D: col = lane&15, row = quad*4 + reg
#pragma unroll
    for (int mi = 0; mi < 2; ++mi) {
      int rbase = m0 + (mh * 2 + mi) * 16 + quad * 4;
#pragma unroll
      for (int reg = 0; reg < 4; ++reg) {
        int row = rbase + reg;
        if (row < NN) {
#pragma unroll
          for (int ni = 0; ni < 6; ++ni) {
            int col = (nh * 6 + ni) * 16 + l16;
            Yg[(size_t)row * 192 + col] = acc[mi][ni][reg];
          }
        }
      }
      if (rbase < NN) {  // rbase % 4 == 0, never straddles 268
#pragma unroll
        for (int ni = 0; ni < 6; ++ni) {
          int col = (nh * 6 + ni) * 16 + l16;
          if (col >= 128) {
            short4v p;
#pragma unroll
            for (int reg = 0; reg < 4; ++reg) p[reg] = f2bf(acc[mi][ni][reg]);
            *(short4v*)(Y2tg + (size_t)(col - 128) * KP + rbase) = p;
          }
        }
      }
    }
  } else if (bx < 1664) {
    // ============ Laplacian build (vectorized scan + zero + writeback) =====
    int l = bx - 640;                // 0..1023 = 8 xcd * 16 g * 8 tiles
    int xcd = l & 7, rest = l >> 3;  // rest 0..127
    int g = xcd + 8 * (rest & 15);
    int tile = rest >> 4;            // 0..7
    int r0 = tile * 34;
    const int* ei = (g < 64) ? (ei1 + (size_t)g * 2 * NE) : (ei2 + (size_t)(g - 64) * 2 * NE);
    const float* ea = (g < 64) ? (ea1 + (size_t)g * NE) : (ea2 + (size_t)(g - 64) * NE);
    int* LrowI = (int*)smem;                      // 34*288 ints = 39,168 B
    float* dv = (float*)(smem + 39168);           // 272 floats
    for (int i = t; i < 34 * 288 / 4; i += 256)   // int4 zero (9.6 iters)
      ((int4*)LrowI)[i] = make_int4(0, 0, 0, 0);
    for (int i = t; i < 272; i += 256) dv[i] = dinv_all[(size_t)g * 272 + i];
    __syncthreads();
#pragma unroll
    for (int i = 0; i < 8; ++i) {
      int e = (i * 256 + t) * 4;
      int4 d4 = *(const int4*)(ei + NE + e);
      int4 s4 = *(const int4*)(ei + e);
      float4 w4 = *(const float4*)(ea + e);
      int ss[4] = {s4.x, s4.y, s4.z, s4.w};
      int dd[4] = {d4.x, d4.y, d4.z, d4.w};
      float ww[4] = {w4.x, w4.y, w4.z, w4.w};
#pragma unroll
      for (int j = 0; j < 4; ++j) {
        int d = dd[j], s = ss[j];
        if (d >= r0 && d < r0 + 34 && s != d) {
          atomicAdd(&LrowI[(d - r0) * 288 + s],
                    (int)lrintf(-dv[s] * ww[j] * dv[d] * 16777216.f));  // ds_add
        }
      }
    }
    __syncthreads();
    short* Lbg = Lb + (size_t)g * 272 * KP + (size_t)r0 * KP;
    for (int i = t; i < 34 * 288 / 8; i += 256) { // short8 writeback (4.8 iters)
      short8 p;
#pragma unroll
      for (int j = 0; j < 8; ++j)
        p[j] = f2bf((float)LrowI[i * 8 + j] * (1.f / 16777216.f));
      *(short8*)(Lbg + (size_t)i * 8) = p;
    }
  } else {
    // ===================== Wc1bT / W4bT tail (megaB inputs) ================
    int idx = (bx - 1664) * 256 + t;  // 0..38399
    if (idx < 112 * KP) {
      int n = idx / KP, k = idx - n * KP;
      float v = (n < 100 && k < 268) ? Wc1[(size_t)k * 100 + n] : 0.f;
      Wc1bT[idx] = f2bf(v);
    } else {
      int i4 = idx - 112 * KP;       // 0..6143
      int n = i4 >> 6, k = i4 & 63;  // n in [0,96), k in [0,64)
      W4bT[i4] = f2bf(W4[(((size_t)(n >> 5)) * 64 + k) * 32 + (n & 31)]);
    }
  }
}

// ---------------------------------------------------------------------------
// Shared mega helpers (R8-verified): L fragment hoist + LDS-B MFMA body.
// ---------------------------------------------------------------------------
#define SP 296
#define NW 8
#define NTHR 512

__device__ __forceinline__ void load_a9(const short* __restrict__ Lbg,
                                        int mt, int l16, int quad, short8* a9) {
  const short* Arow = Lbg + (size_t)(mt * 16 + l16) * KP + quad * 8;
#pragma unroll
  for (int k = 0; k < 9; ++k) a9[k] = *(const short8*)(Arow + k * 32);
}

template <int NTN>
__device__ __forceinline__ void cheb_mm_pre(const short8* a9,
                                            const char* B0, int l16, int quad,
                                            f32x4* acc) {
#pragma unroll
  for (int k = 0; k < 9; ++k) {
#pragma unroll
    for (int nt = 0; nt < NTN; ++nt) {
      short8 bf = *(const short8*)(B0 +
          ((size_t)(nt * 16 + l16) * SP + k * 32 + quad * 8) * 2);
      acc[nt] = __builtin_amdgcn_mfma_f32_16x16x32_bf16(a9[k], bf, acc[nt], 0, 0, 0);
    }
  }
}

// ---------------------------------------------------------------------------
// K3: megaA (R9 verbatim) — P0/P1/P2 by feature half. 256 blocks, 512 thr.
// ---------------------------------------------------------------------------
#define A_Y2H 0
#define A_UTH 18944
__global__ __launch_bounds__(NTHR, 1) void k_megaA(
    const short* __restrict__ Lb, const short* __restrict__ arena,
    const float* __restrict__ Y, const float* __restrict__ b1,
    short* __restrict__ H1G) {
  __shared__ __align__(16) char sm[37888];
  int b = blockIdx.x;
  int xcd = b & 7, idx = b >> 3;
  int g = xcd + 8 * (idx & 15);
  int h = idx >> 4;                    // feature half 0/1
  int t = threadIdx.x;
  int w = t >> 6, lane = t & 63;
  int quad = lane >> 4, l16 = lane & 15;
  const short* Lbg = Lb + (size_t)g * 272 * KP;
  const short* Y2tg = arena + (size_t)g * ARENA_SLAB_S + (size_t)h * 32 * KP;
  const float* Yg = Y + (size_t)g * NN * 192;
  short* H1gg = H1G + (size_t)g * 268 * 64;

  short8 aL0[9], aL1[9], aL2[9];
  load_a9(Lbg, w, l16, quad, aL0);
  load_a9(Lbg, w + 8, l16, quad, aL1);
  if (w == 0) load_a9(Lbg, 16, l16, quad, aL2);

  // P0: stage own 32 Y2t rows; cols >=268 zeroed (poison-safe)
  for (int i = t; i < 32 * 37; i += NTHR) {
    int r = i / 37, c = (i - r * 37) * 8;
    short8 v = {0, 0, 0, 0, 0, 0, 0, 0};
    if (c < 264) {
      v = *(const short8*)(Y2tg + (size_t)r * KP + c);
    } else if (c == 264) {
      v = *(const short8*)(Y2tg + (size_t)r * KP + 264);
      v[4] = 0; v[5] = 0; v[6] = 0; v[7] = 0;
    }
    *(short8*)(sm + A_Y2H + ((size_t)r * SP + c) * 2) = v;
  }
  for (int i = t; i < 32 * 20; i += NTHR) {  // zero Ut K-pad cols 268..288
    int f = i / 20, d = 268 + (i - f * 20);
    *(short*)(sm + A_UTH + ((size_t)f * SP + d) * 2) = 0;
  }
  __syncthreads();

  // P1: Ut[f_loc][d] = bf16(Y1[d][f_glob] + 2*(L@Y2)[d][f_glob])
  {
    auto body = [&](int mt, const short8* a9) {
      int dbase = mt * 16 + quad * 4;
      float yr[2][4];
      if (dbase < NN) {
#pragma unroll
        for (int nt = 0; nt < 2; ++nt)
#pragma unroll
          for (int reg = 0; reg < 4; ++reg)
            yr[nt][reg] = Yg[(size_t)(dbase + reg) * 192 + 64 + h * 32 + nt * 16 + l16];
      }
      f32x4 acc[2];
#pragma unroll
      for (int nt = 0; nt < 2; ++nt) acc[nt] = (f32x4){0.f, 0.f, 0.f, 0.f};
      cheb_mm_pre<2>(a9, sm + A_Y2H, l16, quad, acc);
      if (dbase < NN) {
#pragma unroll
        for (int nt = 0; nt < 2; ++nt) {
          int f_loc = nt * 16 + l16;
          short4v p;
#pragma unroll
          for (int reg = 0; reg < 4; ++reg)
            p[reg] = f2bf(yr[nt][reg] + 2.f * acc[nt][reg]);
          *(short4v*)(sm + A_UTH + ((size_t)f_loc * SP + dbase) * 2) = p;
        }
      }
    };
    body(w, aL0); body(w + 8, aL1); if (w == 0) body(16, aL2);
  }
  __syncthreads();

  // P2: H1[d][f_glob] = relu(Y0 - Y2 + (L@Ut) + b1) -> H1G global
  {
    auto body = [&](int mt, const short8* a9) {
      int dbase = mt * 16 + quad * 4;
      float yr0[2][4], yr2[2][4];
      if (dbase < NN) {
#pragma unroll
        for (int nt = 0; nt < 2; ++nt)
#pragma unroll
          for (int reg = 0; reg < 4; ++reg) {
            int fg = h * 32 + nt * 16 + l16;
            yr0[nt][reg] = Yg[(size_t)(dbase + reg) * 192 + fg];
            yr2[nt][reg] = Yg[(size_t)(dbase + reg) * 192 + 128 + fg];
          }
      }
      f32x4 acc[2];
#pragma unroll
      for (int nt = 0; nt < 2; ++nt) acc[nt] = (f32x4){0.f, 0.f, 0.f, 0.f};
      cheb_mm_pre<2>(a9, sm + A_UTH, l16, quad, acc);
      if (dbase < NN) {
#pragma unroll
        for (int nt = 0; nt < 2; ++nt) {
          int fg = h * 32 + nt * 16 + l16;
          float bb = b1[fg];
#pragma unroll
          for (int reg = 0; reg < 4; ++reg) {
            int d = dbase + reg;
            float v = yr0[nt][reg] - yr2[nt][reg] + acc[nt][reg] + bb;
            H1gg[(size_t)d * 64 + fg] = f2bf(fmaxf(v, 0.f));
          }
        }
      }
    };
    body(w, aL0); body(w + 8, aL1); if (w == 0) body(16, aL2);
  }
}

// ---------------------------------------------------------------------------
// K4: megaB (R9 verbatim) — P3..P6+cls by output-feature 16-group.
// 256 blocks, 512 thr.
// ---------------------------------------------------------------------------
#define B_H1S 0
#define B_W4S 39168
#define B_YB0 52992
#define B_YB1 70400
#define B_YB2 87808
#define B_YBB 105216
#define B_UT2 0
#define B_H2T 9472
#define B_Z1  18944
#define B_W2S 26368
#define B_Z2  52992      // overlays YB0; used only in P6 (after YB0 dead)
#define B_W3S 57088
__global__ __launch_bounds__(NTHR, 1) void k_megaB(
    const short* __restrict__ Lb, const short* __restrict__ H1G,
    const short* __restrict__ W4bT, const short* __restrict__ Wc1bT,
    const float* __restrict__ b4, const float* __restrict__ bc1,
    const float* __restrict__ Wc2, const float* __restrict__ bc2,
    const float* __restrict__ Wc3, const float* __restrict__ bc3,
    float* __restrict__ out) {
  __shared__ __align__(16) char sm[114688];
  int b = blockIdx.x;
  int xcd = b & 7, idx = b >> 3;
  int g = xcd + 8 * (idx & 15);
  int h = idx >> 4;                    // output-feature 16-group 0/1
  int t = threadIdx.x;
  int w = t >> 6, lane = t & 63;
  int quad = lane >> 4, l16 = lane & 15;
  const short* Lbg = Lb + (size_t)g * 272 * KP;
  const short* H1gg = H1G + (size_t)g * 268 * 64;

  short8 aL0[9], aL1[9], aL2[9];
  load_a9(Lbg, w, l16, quad, aL0);
  load_a9(Lbg, w + 8, l16, quad, aL1);
  if (w == 0) load_a9(Lbg, 16, l16, quad, aL2);

  // stage H1s [272][72] from H1G (rows >=268 zero; col group 8 = pad zeros)
  for (int i = t; i < 272 * 9; i += NTHR) {
    int r = i / 9, cg = i - r * 9;
    short8 v = {0, 0, 0, 0, 0, 0, 0, 0};
    if (cg < 8 && r < 268) v = *(const short8*)(H1gg + (size_t)r * 64 + cg * 8);
    *(short8*)(sm + B_H1S + ((size_t)r * 72 + cg * 8) * 2) = v;
  }
  for (int i = t; i < 96 * 8; i += NTHR) {   // W4s [96][72]
    int r = i >> 3, ko = (i & 7) * 8;
    *(short8*)(sm + B_W4S + ((size_t)r * 72 + ko) * 2) =
        *(const short8*)(W4bT + r * 64 + ko);
  }
  for (int i = t; i < 16 * 20; i += NTHR) {  // zero YbB K-pad cols 268..288
    int f = i / 20, d = 268 + (i - f * 20);
    *(short*)(sm + B_YBB + ((size_t)f * SP + d) * 2) = 0;
  }
  __syncthreads();

  // P3: 3 own c-tiles x 17 d-tiles, K=64 over f
  for (int id = w; id < 51; id += NW) {
    int ci = id / 17, nt = id - ci * 17;     // ci 0..2 -> c-tile h + 2*ci
    int ct = h + 2 * ci;
    f32x4 a1 = (f32x4){0.f, 0.f, 0.f, 0.f};
#pragma unroll
    for (int kc = 0; kc < 2; ++kc) {
      short8 af = *(const short8*)(sm + B_W4S +
          ((size_t)(ct * 16 + l16) * 72 + kc * 32 + quad * 8) * 2);
      short8 bf = *(const short8*)(sm + B_H1S +
          ((size_t)(nt * 16 + l16) * 72 + kc * 32 + quad * 8) * 2);
      a1 = __builtin_amdgcn_mfma_f32_16x16x32_bf16(af, bf, a1, 0, 0, 0);
    }
    int d = nt * 16 + l16;
    if (d < NN) {
#pragma unroll
      for (int reg = 0; reg < 4; ++reg) {
        int fl = quad * 4 + reg;             // local row in the 16-tile
        float a = a1[reg];
        if (ci == 0) {
          *(float*)(sm + B_YB0 + ((size_t)fl * 272 + d) * 4) = a;
        } else if (ci == 1) {
          *(float*)(sm + B_YB1 + ((size_t)fl * 272 + d) * 4) = a;
        } else {
          *(float*)(sm + B_YB2 + ((size_t)fl * 272 + d) * 4) = a;
          *(short*)(sm + B_YBB + ((size_t)fl * SP + d) * 2) = f2bf(a);
        }
      }
    }
  }
  __syncthreads();

  // zero Ut2/H2T K-pad cols (regions overlay dead H1s; safe after barrier)
  for (int i = t; i < 16 * 20; i += NTHR) {
    int f = i / 20, d = 268 + (i - f * 20);
    *(short*)(sm + B_UT2 + ((size_t)f * SP + d) * 2) = 0;
    *(short*)(sm + B_H2T + ((size_t)f * SP + d) * 2) = 0;
  }

  // P4: Ut2[f][d] = bf16(Yb1[d][f] + 2*(L@Yb2)[d][f])
  {
    auto body = [&](int mt, const short8* a9) {
      int dbase = mt * 16 + quad * 4;
      float yr[4];
      if (dbase < NN) {
#pragma unroll
        for (int reg = 0; reg < 4; ++reg)
          yr[reg] = *(const float*)(sm + B_YB1 + ((size_t)l16 * 272 + dbase + reg) * 4);
      }
      f32x4 acc1 = (f32x4){0.f, 0.f, 0.f, 0.f};
      cheb_mm_pre<1>(a9, sm + B_YBB, l16, quad, &acc1);
      if (dbase < NN) {
        short4v p;
#pragma unroll
        for (int reg = 0; reg < 4; ++reg)
          p[reg] = f2bf(yr[reg] + 2.f * acc1[reg]);
        *(short4v*)(sm + B_UT2 + ((size_t)l16 * SP + dbase) * 2) = p;
      }
    };
    body(w, aL0); body(w + 8, aL1); if (w == 0) body(16, aL2);
  }
  __syncthreads();

  // P5: H2T[f][d] = relu(Yb0 - Yb2 + (L@Ut2) + b4[f_glob])
  {
    float bb = b4[h * 16 + l16];
    auto body = [&](int mt, const short8* a9) {
      int dbase = mt * 16 + quad * 4;
      float yr0[4], yr2[4];
      if (dbase < NN) {
#pragma unroll
        for (int reg = 0; reg < 4; ++reg) {
          yr0[reg] = *(const float*)(sm + B_YB0 + ((size_t)l16 * 272 + dbase + reg) * 4);
          yr2[reg] = *(const float*)(sm + B_YB2 + ((size_t)l16 * 272 + dbase + reg) * 4);
        }
      }
      f32x4 acc1 = (f32x4){0.f, 0.f, 0.f, 0.f};
      cheb_mm_pre<1>(a9, sm + B_UT2, l16, quad, &acc1);
      if (dbase < NN) {
        short4v p;
#pragma unroll
        for (int reg = 0; reg < 4; ++reg) {
          float v = yr0[reg] - yr2[reg] + acc1[reg] + bb;
          p[reg] = f2bf(fmaxf(v, 0.f));
        }
        *(short4v*)(sm + B_H2T + ((size_t)l16 * SP + dbase) * 2) = p;
      }
    };
    body(w, aL0); body(w + 8, aL1); if (w == 0) body(16, aL2);
  }
  __syncthreads();

  // P6-L1: Z1[f][col] MFMA (A = H2T rows f, 1 m-tile; B = Wc1bT, K=288)
  for (int id = w; id < 7; id += NW) {
    f32x4 a1 = (f32x4){0.f, 0.f, 0.f, 0.f};
#pragma unroll
    for (int k = 0; k < 9; ++k) {
      short8 af = *(const short8*)(sm + B_H2T +
          ((size_t)l16 * SP + k * 32 + quad * 8) * 2);
      short8 bf = *(const short8*)(Wc1bT + (size_t)(id * 16 + l16) * KP + k * 32 + quad * 8);
      a1 = __builtin_amdgcn_mfma_f32_16x16x32_bf16(af, bf, a1, 0, 0, 0);
    }
    int col = id * 16 + l16;
    if (col < 100) {
      float bb = bc1[col];
#pragma unroll
      for (int reg = 0; reg < 4; ++reg)
        *(float*)(sm + B_Z1 + ((size_t)(quad * 4 + reg) * 116 + col) * 4) =
            fmaxf(a1[reg] + bb, 0.f);
    }
  }
  for (int i = t; i < 100 * 64; i += NTHR) { // stage W2s [100][64]
    int rr = i >> 6, c = i & 63;
    *(float*)(sm + B_W2S + ((size_t)rr * 64 + c) * 4) =
        (c < 60) ? Wc2[(size_t)rr * 60 + c] : 0.f;
  }
  if (t < 64) *(float*)(sm + B_W3S + (size_t)t * 4) = (t < 60) ? Wc3[t] : 0.f;
  __syncthreads();
  if (t < 64) {                              // L2: 16 rows x 64 cols
    int r2 = (t >> 3) * 2;
    int c8 = (t & 7) * 8;
    float a2[2][8];
#pragma unroll
    for (int i = 0; i < 2; ++i)
#pragma unroll
      for (int j = 0; j < 8; ++j) a2[i][j] = 0.f;
    const float* Z1p = (const float*)(sm + B_Z1);
    const float* W2p = (const float*)(sm + B_W2S);
#pragma unroll 4
    for (int k = 0; k < 100; ++k) {
      float x0 = Z1p[(size_t)r2 * 116 + k], x1 = Z1p[(size_t)(r2 + 1) * 116 + k];
      float4 wA = *(const float4*)(W2p + (size_t)k * 64 + c8);
      float4 wB = *(const float4*)(W2p + (size_t)k * 64 + c8 + 4);
      float wv[8] = {wA.x, wA.y, wA.z, wA.w, wB.x, wB.y, wB.z, wB.w};
#pragma unroll
      for (int j = 0; j < 8; ++j) { a2[0][j] += x0 * wv[j]; a2[1][j] += x1 * wv[j]; }
    }
    float* Z2p = (float*)(sm + B_Z2);
#pragma unroll
    for (int j = 0; j < 8; ++j) {
      int c = c8 + j;
      float bb = (c < 60) ? bc2[c] : 0.f;
      Z2p[(size_t)r2 * 64 + c] = fmaxf(a2[0][j] + bb, 0.f);
      Z2p[(size_t)(r2 + 1) * 64 + c] = fmaxf(a2[1][j] + bb, 0.f);
    }
  }
  __syncthreads();
  if (t < 16) {                              // L3: out = Z2 . Wc3 + bc3
    const float* Z2p = (const float*)(sm + B_Z2);
    const float* w3p = (const float*)(sm + B_W3S);
    float acc3 = bc3[0];
#pragma unroll
    for (int k = 0; k < 60; ++k) acc3 += Z2p[(size_t)t * 64 + k] * w3p[k];
    out[(size_t)g * 32 + h * 16 + t] = acc3;
  }
}

extern "C" void kernel_launch(void* const* d_in, const int* in_sizes, int n_in,
                              void* d_out, int out_size, void* d_ws, size_t ws_size,
                              hipStream_t stream) {
  (void)in_sizes; (void)n_in; (void)out_size; (void)ws_size;
  const float* x1  = (const float*)d_in[0];
  const int*   ei1 = (const int*)d_in[1];
  const float* ea1 = (const float*)d_in[2];
  const float* x2  = (const float*)d_in[3];
  const int*   ei2 = (const int*)d_in[4];
  const float* ea2 = (const float*)d_in[5];
  const float* W1  = (const float*)d_in[6];
  const float* b1  = (const float*)d_in[7];
  const float* W4  = (const float*)d_in[8];
  const float* b4  = (const float*)d_in[9];
  const float* Wc1 = (const float*)d_in[10];
  const float* bc1 = (const float*)d_in[11];
  const float* Wc2 = (const float*)d_in[12];
  const float* bc2 = (const float*)d_in[13];
  const float* Wc3 = (const float*)d_in[14];
  const float* bc3 = (const float*)d_in[15];

  char* ws = (char*)d_ws;
  float* dinv  = (float*)(ws + OFF_DINV);
  short* arena = (short*)(ws + OFF_ARENA);
  short* WbT   = (short*)(ws + OFF_WBT);
  short* Wc1bT = (short*)(ws + OFF_WC1BT);
  short* W4bT  = (short*)(ws + OFF_W4BT);
  short* Lb    = (short*)(ws + OFF_LB);
  float* Y     = (float*)(ws + OFF_Y);
  short* H1G   = (short*)(ws + OFF_H1G);
  float* out   = (float*)d_out;

  // L1: deg -> dinv (vectorized scan) + WbT conversion
  k_prep<<<182, 1024, 0, stream>>>(ei1, ea1, ei2, ea2, W1, WbT, dinv);
  // L2: Laplacian build (fully vectorized) || gemm1 (prefetched) || conv tail
  k_build_gemm1<<<1814, 256, 0, stream>>>(ei1, ea1, ei2, ea2, dinv, Lb,
                                          x1, x2, WbT, Wc1, W4, Y, arena,
                                          Wc1bT, W4bT);
  // L3: megaA — P0-P2, feature-halved, 256 blocks (full machine)
  k_megaA<<<256, NTHR, 0, stream>>>(Lb, arena, Y, b1, H1G);
  // L4: megaB — P3-P6+cls, feature-16-split, 256 blocks (full machine)
  k_megaB<<<256, NTHR, 0, stream>>>(Lb, H1G, W4bT, Wc1bT,
                                    b4, bc1, Wc2, bc2, Wc3, bc3, out);
}